// Round 16
// baseline (2941.798 us; speedup 1.0000x reference)
//
#include <hip/hip_runtime.h>
#include <hip/hip_bf16.h>
#include <math.h>

#define S_LEN 2048
#define HID   1280
#define NHEADS 16
#define HDIM  80
#define HDP   96
#define VROWS 96
#define LAYERS 8
#define IDIM  3420
#define IDIMP 3456
#define MERGED 5120
#define OUTD  3584

typedef __attribute__((ext_vector_type(8))) short short8;
typedef __attribute__((ext_vector_type(4))) float f32x4;
typedef __attribute__((ext_vector_type(16))) float f32x16;
typedef unsigned int u32;
typedef __attribute__((ext_vector_type(4))) u32 u32x4;
typedef __attribute__((address_space(1))) const u32* gptr_t;
typedef __attribute__((address_space(3))) u32* lptr_t;

__device__ inline unsigned short f2b(float f){
  __hip_bfloat16 b = __float2bfloat16(f);
  return __builtin_bit_cast(unsigned short, b);
}
__device__ inline float b2f(unsigned short u){
  return __bfloat162float(__builtin_bit_cast(__hip_bfloat16, u));
}
__device__ inline unsigned pk2(float lo, float hi){
  return (unsigned)f2b(lo) | ((unsigned)f2b(hi) << 16);
}

// hidden f32 -> bf16 residual stream
__global__ __launch_bounds__(256) void h2b_kernel(
    const float* __restrict__ in, unsigned short* __restrict__ out)
{
  size_t i = ((size_t)blockIdx.x * 256 + threadIdx.x) * 8;
  f32x4 a = *(const f32x4*)(in + i);
  f32x4 b = *(const f32x4*)(in + i + 4);
  u32x4 o = {pk2(a[0], a[1]), pk2(a[2], a[3]), pk2(b[0], b[1]), pk2(b[2], b[3])};
  *(u32x4*)(out + i) = o;
}

// interleaved bias: even = gate, odd = up
__global__ __launch_bounds__(256) void concat_bias_kernel(
    const float* __restrict__ g, const float* __restrict__ u, float* __restrict__ o)
{
  int L = blockIdx.y;
  int n = blockIdx.x * 256 + threadIdx.x;
  if (n >= 2 * IDIMP) return;
  int c = n >> 1, which = n & 1;
  float v = 0.f;
  if (c < IDIM) v = which ? u[(size_t)L * IDIM + c] : g[(size_t)L * IDIM + c];
  o[(size_t)L * 2 * IDIMP + n] = v;
}

// ---------------- RMSNorm: bf16 in -> bf16 out (vectorized) ---------------
__global__ __launch_bounds__(256) void rmsnorm_kernel(
    const unsigned short* __restrict__ x, const float* __restrict__ w,
    unsigned short* __restrict__ out, int H)
{
  int s = blockIdx.x;
  const unsigned short* row = x + (size_t)s * H;
  const int c8 = threadIdx.x;
  const bool act = c8 < (H >> 3);
  float vals[8];
  float ss = 0.f;
  if (act){
    short8 v8 = *(const short8*)(row + c8 * 8);
    #pragma unroll
    for (int j = 0; j < 8; ++j){ vals[j] = b2f((unsigned short)v8[j]); ss += vals[j] * vals[j]; }
  }
  #pragma unroll
  for (int off = 32; off >= 1; off >>= 1) ss += __shfl_xor(ss, off, 64);
  __shared__ float red[4];
  if ((threadIdx.x & 63) == 0) red[threadIdx.x >> 6] = ss;
  __syncthreads();
  ss = red[0] + red[1] + red[2] + red[3];
  float rs = rsqrtf(ss / H + 1e-6f);
  if (act){
    f32x4 w0 = *(const f32x4*)(w + c8 * 8);
    f32x4 w1 = *(const f32x4*)(w + c8 * 8 + 4);
    u32x4 o = {pk2(vals[0] * rs * w0[0], vals[1] * rs * w0[1]),
               pk2(vals[2] * rs * w0[2], vals[3] * rs * w0[3]),
               pk2(vals[4] * rs * w1[0], vals[5] * rs * w1[1]),
               pk2(vals[6] * rs * w1[2], vals[7] * rs * w1[3])};
    *(u32x4*)(out + (size_t)s * H + c8 * 8) = o;
  }
}

// ---------------- bf16 MFMA GEMM, f32 B-weights reg-staged -----------------
// A: bf16 [M][lda] via global_load_lds. B: f32 weights converted on the fly
// (issue loads early, cvt+ds_write after compute — T14 async-stage split).
// ILV=1: row n -> (n&1 ? Bf1 : Bf0)[n>>1], valid while (n>>1) < NactB.
// EPI 0: f32 = acc+bias   1: bf16 = b2f(res)+acc+bias
// EPI 2: bf16 = gelu(acc+bias)   3: bf16 = acc+bias   4: bf16 silu-mul
template<int EPI, int BM, int BN, int ILV>
__global__ __launch_bounds__(256) void gemm_kernel(
    const unsigned short* __restrict__ A, int lda,
    const float* __restrict__ Bf0, const float* __restrict__ Bf1,
    int ldbf, int NactB, int Kact,
    const float* __restrict__ bias, int Nact,
    void* __restrict__ Cv, int ldc,
    const void* __restrict__ res,
    int K)
{
  constexpr int MI = BM / 64;
  constexpr int NI = BN / 64;
  constexpr int NCH = BN / 64;          // B chunks per wave
  __shared__ __align__(16) unsigned short As[2][BM * 32];
  __shared__ __align__(16) unsigned short Bs[2][BN * 32];
  const int tid  = threadIdx.x;
  const int lane = tid & 63;
  const int wave = tid >> 6;
  const int wm = wave >> 1, wn = wave & 1;
  const int gx = gridDim.x, gy = gridDim.y;
  const int total = gx * gy;
  const int orig = blockIdx.y * gx + blockIdx.x;
  const int q8 = total >> 3, r8 = total & 7;
  const int xcd = orig & 7, loc = orig >> 3;
  const int wg = (xcd < r8 ? xcd * (q8 + 1) : r8 * (q8 + 1) + (xcd - r8) * q8) + loc;
  const int m0 = (wg % gy) * BM, n0 = (wg / gy) * BN;
  const int l31 = lane & 31, lh1 = lane >> 5;
  const int lrow = lane >> 2;
  const int lcol = lane & 3;
  f32x16 acc[MI][NI] = {};

  auto stageA = [&](int bufi, int k0){
    #pragma unroll
    for (int j = 0; j < BM / 64; ++j){
      int chunk = wave * (BM / 64) + j;
      int row  = chunk * 16 + lrow;
      int slot = lcol ^ ((row >> 1) & 3);
      const unsigned short* srcA = A + (size_t)(m0 + row) * lda + k0 + slot * 8;
      __builtin_amdgcn_global_load_lds((gptr_t)srcA, (lptr_t)&As[bufi][chunk * 512], 16, 0, 0);
    }
  };
  // issue f32 B loads for k-step (into regs)
  auto loadB = [&](int k0, f32x4 bl[NCH][2]){
    #pragma unroll
    for (int j = 0; j < NCH; ++j){
      int chunk = wave * NCH + j;
      int row  = chunk * 16 + lrow;
      int slot = lcol ^ ((row >> 1) & 3);
      int col0 = k0 + slot * 8;
      int gn = n0 + row;
      const float* src;
      bool vrow;
      if (ILV){
        int nr = gn >> 1;
        vrow = nr < NactB;
        src = (gn & 1 ? Bf1 : Bf0) + (size_t)nr * ldbf;
      } else {
        vrow = gn < NactB;
        src = Bf0 + (size_t)gn * ldbf;
      }
      if (vrow && col0 + 8 <= Kact){
        bl[j][0] = *(const f32x4*)(src + col0);
        bl[j][1] = *(const f32x4*)(src + col0 + 4);
      } else {
        #pragma unroll
        for (int e = 0; e < 4; ++e){
          bl[j][0][e] = (vrow && col0 + e     < Kact) ? src[col0 + e]     : 0.f;
          bl[j][1][e] = (vrow && col0 + 4 + e < Kact) ? src[col0 + 4 + e] : 0.f;
        }
      }
    }
  };
  auto writeB = [&](int bufi, f32x4 bl[NCH][2]){
    #pragma unroll
    for (int j = 0; j < NCH; ++j){
      int chunk = wave * NCH + j;
      u32x4 ov = {pk2(bl[j][0][0], bl[j][0][1]), pk2(bl[j][0][2], bl[j][0][3]),
                  pk2(bl[j][1][0], bl[j][1][1]), pk2(bl[j][1][2], bl[j][1][3])};
      *(u32x4*)&Bs[bufi][chunk * 512 + lane * 8] = ov;
    }
  };

  const int nt = K >> 5;
  f32x4 bl[NCH][2];
  loadB(0, bl);
  stageA(0, 0);
  writeB(0, bl);
  __syncthreads();
  int buf = 0;
  for (int t = 0; t < nt; ++t){
    if (t + 1 < nt){
      loadB((t + 1) << 5, bl);     // issue f32 loads (latency hides under MFMA)
      stageA(buf ^ 1, (t + 1) << 5);
    }
    short8 af[MI][2], bfr[NI][2];
    #pragma unroll
    for (int mi = 0; mi < MI; ++mi){
      int r = wm * (BM / 2) + mi * 32 + l31;
      int sw = (r >> 1) & 3;
      #pragma unroll
      for (int ks = 0; ks < 2; ++ks){
        int sl = (ks * 2 + lh1) ^ sw;
        af[mi][ks] = *(const short8*)&As[buf][r * 32 + sl * 8];
      }
    }
    #pragma unroll
    for (int ni = 0; ni < NI; ++ni){
      int r = wn * (BN / 2) + ni * 32 + l31;
      int sw = (r >> 1) & 3;
      #pragma unroll
      for (int ks = 0; ks < 2; ++ks){
        int sl = (ks * 2 + lh1) ^ sw;
        bfr[ni][ks] = *(const short8*)&Bs[buf][r * 32 + sl * 8];
      }
    }
    #pragma unroll
    for (int mi = 0; mi < MI; ++mi)
      #pragma unroll
      for (int ni = 0; ni < NI; ++ni)
        #pragma unroll
        for (int ks = 0; ks < 2; ++ks)
          acc[mi][ni] = __builtin_amdgcn_mfma_f32_32x32x16_bf16(
              af[mi][ks], bfr[ni][ks], acc[mi][ni], 0, 0, 0);
    if (t + 1 < nt) writeB(buf ^ 1, bl);   // cvt + ds_write after compute
    __syncthreads();
    buf ^= 1;
  }

  // C/D 32x32 layout: col = l31, row = (r&3) + 8*(r>>2) + 4*lh1
  #pragma unroll
  for (int mi = 0; mi < MI; ++mi){
    int mrow0 = m0 + wm * (BM / 2) + mi * 32 + 4 * lh1;
    #pragma unroll
    for (int ni = 0; ni < NI; ++ni){
      int gn = n0 + wn * (BN / 2) + ni * 32 + l31;
      float bv = (gn < Nact) ? bias[gn] : 0.f;
      #pragma unroll
      for (int r = 0; r < 16; ++r){
        int row = mrow0 + (r & 3) + 8 * (r >> 2);
        float v = acc[mi][ni][r] + bv;
        if (EPI == 4){
          float partner = __shfl_xor(v, 1);
          if (!(l31 & 1)){
            float rr = v / (1.f + __expf(-v)) * partner;   // silu(gate)*up
            ((unsigned short*)Cv)[(size_t)row * ldc + (gn >> 1)] = f2b(rr);
          }
        } else {
          size_t offc = (size_t)row * ldc + gn;
          if (EPI == 0)      ((float*)Cv)[offc] = v;
          else if (EPI == 1) ((unsigned short*)Cv)[offc] =
                                f2b(v + b2f(((const unsigned short*)res)[offc]));
          else if (EPI == 2) ((unsigned short*)Cv)[offc] = f2b(0.5f * v * (1.0f + erff(v * 0.70710678118f)));
          else               ((unsigned short*)Cv)[offc] = f2b(v);
        }
      }
    }
  }
}

// ---------------- RoPE + QKV split to global (full-attn layers only) ------
__global__ __launch_bounds__(256) void rope_split_kernel(
    const unsigned short* __restrict__ qkv, const float* __restrict__ cosT,
    const float* __restrict__ sinT,
    unsigned short* __restrict__ qo, unsigned short* __restrict__ ko,
    unsigned short* __restrict__ vt)
{
  __shared__ unsigned short vtile[80][128];
  int id = blockIdx.y * 16 + blockIdx.x;
  int logical = ((id & 7) << 5) + (id >> 3);
  const int h = logical & 15;
  const int s0 = (logical >> 4) * 128;
  const int t = threadIdx.x;
  const int sr = t >> 1, half = t & 1;
  const int s = s0 + sr;
  const unsigned short* row = qkv + (size_t)s * 3840 + h * 80;
  const float* crow = cosT + (size_t)s * 80;
  const float* srow = sinT + (size_t)s * 80;
  const float sgn = half ? 1.f : -1.f;
  #pragma unroll
  for (int g = 0; g < 5; ++g){
    int d  = half * 40 + g * 8;
    int dp = 40 - half * 40 + g * 8;
    short8 q8  = *(const short8*)(row + d);
    short8 k8  = *(const short8*)(row + 1280 + d);
    short8 qp8 = *(const short8*)(row + dp);
    short8 kp8 = *(const short8*)(row + 1280 + dp);
    short8 v8  = *(const short8*)(row + 2560 + d);
    f32x4 c0  = *(const f32x4*)(crow + d);
    f32x4 c1  = *(const f32x4*)(crow + d + 4);
    f32x4 sn0 = *(const f32x4*)(srow + d);
    f32x4 sn1 = *(const f32x4*)(srow + d + 4);
    float cc[8] = {c0[0], c0[1], c0[2], c0[3], c1[0], c1[1], c1[2], c1[3]};
    float ss[8] = {sn0[0], sn0[1], sn0[2], sn0[3], sn1[0], sn1[1], sn1[2], sn1[3]};
    short8 qo8, ko8;
    #pragma unroll
    for (int j = 0; j < 8; ++j){
      float qv = b2f((unsigned short)q8[j]);
      float kv = b2f((unsigned short)k8[j]);
      float qr = sgn * b2f((unsigned short)qp8[j]);
      float kr = sgn * b2f((unsigned short)kp8[j]);
      qo8[j] = (short)f2b(qv * cc[j] + qr * ss[j]);
      ko8[j] = (short)f2b(kv * cc[j] + kr * ss[j]);
      vtile[d + j][sr] = (unsigned short)v8[j];
    }
    size_t qkoff = ((size_t)h * S_LEN + s) * HDP + d;
    *(short8*)(qo + qkoff) = qo8;
    *(short8*)(ko + qkoff) = ko8;
  }
  {
    short8 z = {};
    size_t poff = ((size_t)h * S_LEN + s) * HDP + 80 + half * 8;
    *(short8*)(qo + poff) = z;
    *(short8*)(ko + poff) = z;
  }
  __syncthreads();
  #pragma unroll
  for (int it = 0; it < 5; ++it){
    int j = t + it * 256;
    int d = j >> 4, ch = j & 15;
    u32x4 v = *(const u32x4*)&vtile[d][ch * 8];
    *(u32x4*)(vt + ((size_t)h * VROWS + d) * S_LEN + s0 + ch * 8) = v;
  }
}

// ---------------- FUSED RoPE + windowed flash (6 of 8 layers) --------------
#define QKPAD 104
#define VPAD  136
__global__ __launch_bounds__(256) void rope_window_kernel(
    const unsigned short* __restrict__ qkv, const float* __restrict__ cosT,
    const float* __restrict__ sinT, unsigned short* __restrict__ out)
{
  __shared__ __align__(16) unsigned short qs[128][QKPAD];   // reused as ot
  __shared__ __align__(16) unsigned short ks[128][QKPAD];
  __shared__ __align__(16) unsigned short vtile[96][VPAD];
  unsigned short (*ot)[32][88] = (unsigned short(*)[32][88])&qs[0][0];
  int id = blockIdx.y * 16 + blockIdx.x;
  int logical = ((id & 7) << 5) + (id >> 3);
  const int h = logical & 15;
  const int s0 = (logical >> 4) * 128;
  const int t = threadIdx.x;
  {
    const int sr = t >> 1, half = t & 1;
    const int s = s0 + sr;
    const unsigned short* row = qkv + (size_t)s * 3840 + h * 80;
    const float* crow = cosT + (size_t)s * 80;
    const float* srow = sinT + (size_t)s * 80;
    const float sgn = half ? 1.f : -1.f;
    #pragma unroll
    for (int g = 0; g < 5; ++g){
      int d  = half * 40 + g * 8;
      int dp = 40 - half * 40 + g * 8;
      short8 q8  = *(const short8*)(row + d);
      short8 k8  = *(const short8*)(row + 1280 + d);
      short8 qp8 = *(const short8*)(row + dp);
      short8 kp8 = *(const short8*)(row + 1280 + dp);
      short8 v8  = *(const short8*)(row + 2560 + d);
      f32x4 c0  = *(const f32x4*)(crow + d);
      f32x4 c1  = *(const f32x4*)(crow + d + 4);
      f32x4 sn0 = *(const f32x4*)(srow + d);
      f32x4 sn1 = *(const f32x4*)(srow + d + 4);
      float cc[8] = {c0[0], c0[1], c0[2], c0[3], c1[0], c1[1], c1[2], c1[3]};
      float ss[8] = {sn0[0], sn0[1], sn0[2], sn0[3], sn1[0], sn1[1], sn1[2], sn1[3]};
      short8 qo8, ko8;
      #pragma unroll
      for (int j = 0; j < 8; ++j){
        float qv = b2f((unsigned short)q8[j]);
        float kv = b2f((unsigned short)k8[j]);
        float qr = sgn * b2f((unsigned short)qp8[j]);
        float kr = sgn * b2f((unsigned short)kp8[j]);
        qo8[j] = (short)f2b(qv * cc[j] + qr * ss[j]);
        ko8[j] = (short)f2b(kv * cc[j] + kr * ss[j]);
        vtile[d + j][sr] = (unsigned short)v8[j];
      }
      *(short8*)&qs[sr][d] = qo8;
      *(short8*)&ks[sr][d] = ko8;
    }
    short8 z = {};
    *(short8*)&qs[sr][80 + half * 8] = z;
    *(short8*)&ks[sr][80 + half * 8] = z;
    #pragma unroll
    for (int r9 = 0; r9 < 2; ++r9){
      int task = t + r9 * 256;
      if (task < 16 * 17){
        int rr = task / 17, cc2 = (task % 17) * 8;
        *(short8*)&vtile[80 + rr][cc2] = z;
      }
    }
  }
  __syncthreads();

  const int lane = t & 63;
  const int w = t >> 6;
  const int l31 = lane & 31, lh1 = lane >> 5;
  const int qrl = w * 32;
  const int kv0 = (w >> 1) * 64;

  short8 qa[5];
  #pragma unroll
  for (int kc = 0; kc < 5; ++kc)
    qa[kc] = *(const short8*)&qs[qrl + l31][kc * 16 + lh1 * 8];
  __syncthreads();

  float m_ = -1e30f, l_ = 0.f;
  f32x16 o0 = {}, o1 = {}, o2 = {};
  const float scale = 0.11180339887498949f;

  #pragma unroll
  for (int step = 0; step < 2; ++step){
    int kvl = kv0 + step * 32;
    f32x16 sc = {};
    __builtin_amdgcn_s_setprio(1);
    #pragma unroll
    for (int kc = 0; kc < 5; ++kc){
      short8 kf = *(const short8*)&ks[kvl + l31][kc * 16 + lh1 * 8];
      sc = __builtin_amdgcn_mfma_f32_32x32x16_bf16(kf, qa[kc], sc, 0, 0, 0);
    }
    __builtin_amdgcn_s_setprio(0);
    float tmax = sc[0];
    #pragma unroll
    for (int i = 1; i < 16; ++i) tmax = fmaxf(tmax, sc[i]);
    tmax = fmaxf(tmax, __shfl_xor(tmax, 32)) * scale;
    if (!__all(tmax <= m_ + 8.f)){
      float mnew = fmaxf(m_, tmax);
      float corr = __expf(m_ - mnew);
      l_ *= corr;
      #pragma unroll
      for (int i = 0; i < 16; ++i){ o0[i] *= corr; o1[i] *= corr; o2[i] *= corr; }
      m_ = mnew;
    }
    float p[16];
    float rs = 0.f;
    #pragma unroll
    for (int i = 0; i < 16; ++i){ p[i] = __expf(sc[i] * scale - m_); rs += p[i]; }
    rs += __shfl_xor(rs, 32);
    l_ += rs;
    unsigned wd0[4], wd1[4];
    #pragma unroll
    for (int j = 0; j < 2; ++j){
      unsigned Aj = pk2(p[2 * j],     p[2 * j + 1]);
      unsigned Bj = pk2(p[4 + 2 * j], p[4 + 2 * j + 1]);
      unsigned t0 = __shfl_xor(Aj, 32);
      unsigned t1 = __shfl_xor(Bj, 32);
      wd0[j]     = lh1 ? t1 : Aj;
      wd0[2 + j] = lh1 ? Bj : t0;
      Aj = pk2(p[8 + 2 * j],  p[8 + 2 * j + 1]);
      Bj = pk2(p[12 + 2 * j], p[12 + 2 * j + 1]);
      t0 = __shfl_xor(Aj, 32);
      t1 = __shfl_xor(Bj, 32);
      wd1[j]     = lh1 ? t1 : Aj;
      wd1[2 + j] = lh1 ? Bj : t0;
    }
    __builtin_amdgcn_s_setprio(1);
    #pragma unroll
    for (int kc2 = 0; kc2 < 2; ++kc2){
      u32x4 uw = kc2 ? u32x4{wd1[0], wd1[1], wd1[2], wd1[3]}
                     : u32x4{wd0[0], wd0[1], wd0[2], wd0[3]};
      short8 pb = __builtin_bit_cast(short8, uw);
      int sv = kvl + kc2 * 16 + lh1 * 8;
      o0 = __builtin_amdgcn_mfma_f32_32x32x16_bf16(
          *(const short8*)&vtile[l31][sv],      pb, o0, 0, 0, 0);
      o1 = __builtin_amdgcn_mfma_f32_32x32x16_bf16(
          *(const short8*)&vtile[32 + l31][sv], pb, o1, 0, 0, 0);
      o2 = __builtin_amdgcn_mfma_f32_32x32x16_bf16(
          *(const short8*)&vtile[64 + l31][sv], pb, o2, 0, 0, 0);
    }
    __builtin_amdgcn_s_setprio(0);
  }

  float inv = 1.f / l_;
  #pragma unroll
  for (int r = 0; r < 16; ++r){
    int dl = (r & 3) + 8 * (r >> 2) + 4 * lh1;
    ot[w][l31][dl]      = f2b(o0[r] * inv);
    ot[w][l31][32 + dl] = f2b(o1[r] * inv);
    if (dl < 16) ot[w][l31][64 + dl] = f2b(o2[r] * inv);
  }
  int qq = lane >> 1, half2 = lane & 1;
  #pragma unroll
  for (int j = 0; j < 20; ++j){
    unsigned v = *(const unsigned*)&ot[w][qq][half2 * 40 + j * 2];
    *(unsigned*)&out[(size_t)(s0 + qrl + qq) * HID + h * HDIM + half2 * 40 + j * 2] = v;
  }
}

// ---------------- Flash attention for FULL layers (split-kv in-block) ------
__global__ __launch_bounds__(256) void flash_full_kernel(
    const unsigned short* __restrict__ q, const unsigned short* __restrict__ k,
    const unsigned short* __restrict__ vt, unsigned short* __restrict__ out)
{
  const int lane = threadIdx.x & 63;
  const int w = threadIdx.x >> 6;
  const int l31 = lane & 31, lh1 = lane >> 5;
  int id = blockIdx.y * gridDim.x + blockIdx.x;
  int logical = ((id & 7) << 7) + (id >> 3);
  const int h = logical >> 6;
  const int qr = (logical & 63) * 32;
  const unsigned short* qh = q + (size_t)h * S_LEN * HDP;
  const unsigned short* kh = k + (size_t)h * S_LEN * HDP;
  const unsigned short* vh = vt + (size_t)h * VROWS * S_LEN;

  short8 qa[5];
  #pragma unroll
  for (int kc = 0; kc < 5; ++kc)
    qa[kc] = *(const short8*)(qh + (size_t)(qr + l31) * HDP + kc * 16 + lh1 * 8);

  float m_ = -1e30f, l_ = 0.f;
  f32x16 o0 = {}, o1 = {}, o2 = {};
  const float scale = 0.11180339887498949f;

  for (int kvt = w * 512; kvt < w * 512 + 512; kvt += 32){
    f32x16 sc = {};
    __builtin_amdgcn_s_setprio(1);
    #pragma unroll
    for (int kc = 0; kc < 5; ++kc){
      short8 kf = *(const short8*)(kh + (size_t)(kvt + l31) * HDP + kc * 16 + lh1 * 8);
      sc = __builtin_amdgcn_mfma_f32_32x32x16_bf16(kf, qa[kc], sc, 0, 0, 0);
    }
    __builtin_amdgcn_s_setprio(0);
    float t = sc[0];
    #pragma unroll
    for (int i = 1; i < 16; ++i) t = fmaxf(t, sc[i]);
    t = fmaxf(t, __shfl_xor(t, 32)) * scale;
    if (!__all(t <= m_ + 8.f)){
      float mnew = fmaxf(m_, t);
      float corr = __expf(m_ - mnew);
      l_ *= corr;
      #pragma unroll
      for (int i = 0; i < 16; ++i){ o0[i] *= corr; o1[i] *= corr; o2[i] *= corr; }
      m_ = mnew;
    }
    float p[16];
    float rs = 0.f;
    #pragma unroll
    for (int i = 0; i < 16; ++i){ p[i] = __expf(sc[i] * scale - m_); rs += p[i]; }
    rs += __shfl_xor(rs, 32);
    l_ += rs;
    unsigned wd0[4], wd1[4];
    #pragma unroll
    for (int j = 0; j < 2; ++j){
      unsigned Aj = pk2(p[2 * j],     p[2 * j + 1]);
      unsigned Bj = pk2(p[4 + 2 * j], p[4 + 2 * j + 1]);
      unsigned t0 = __shfl_xor(Aj, 32);
      unsigned t1 = __shfl_xor(Bj, 32);
      wd0[j]     = lh1 ? t1 : Aj;
      wd0[2 + j] = lh1 ? Bj : t0;
      Aj = pk2(p[8 + 2 * j],  p[8 + 2 * j + 1]);
      Bj = pk2(p[12 + 2 * j], p[12 + 2 * j + 1]);
      t0 = __shfl_xor(Aj, 32);
      t1 = __shfl_xor(Bj, 32);
      wd1[j]     = lh1 ? t1 : Aj;
      wd1[2 + j] = lh1 ? Bj : t0;
    }
    __builtin_amdgcn_s_setprio(1);
    #pragma unroll
    for (int kc2 = 0; kc2 < 2; ++kc2){
      u32x4 uw = kc2 ? u32x4{wd1[0], wd1[1], wd1[2], wd1[3]}
                     : u32x4{wd0[0], wd0[1], wd0[2], wd0[3]};
      short8 pb = __builtin_bit_cast(short8, uw);
      const unsigned short* vb = vh + kvt + kc2 * 16 + lh1 * 8;
      o0 = __builtin_amdgcn_mfma_f32_32x32x16_bf16(
          *(const short8*)(vb + (size_t)(l31)      * S_LEN), pb, o0, 0, 0, 0);
      o1 = __builtin_amdgcn_mfma_f32_32x32x16_bf16(
          *(const short8*)(vb + (size_t)(32 + l31) * S_LEN), pb, o1, 0, 0, 0);
      o2 = __builtin_amdgcn_mfma_f32_32x32x16_bf16(
          *(const short8*)(vb + (size_t)(64 + l31) * S_LEN), pb, o2, 0, 0, 0);
    }
    __builtin_amdgcn_s_setprio(0);
  }

  __shared__ float of[80][33];
  __shared__ float mlsh[4][32][2];
  __shared__ float Lsh[32];
  __shared__ unsigned short ot2[32][88];
  if (lane < 32){ mlsh[w][l31][0] = m_; mlsh[w][l31][1] = l_; }
  __syncthreads();
  float M = fmaxf(fmaxf(mlsh[0][l31][0], mlsh[1][l31][0]),
                  fmaxf(mlsh[2][l31][0], mlsh[3][l31][0]));
  float L = 0.f;
  #pragma unroll
  for (int c = 0; c < 4; ++c) L += __expf(mlsh[c][l31][0] - M) * mlsh[c][l31][1];
  float wgt = __expf(m_ - M);
  if (w == 0 && lane < 32) Lsh[l31] = L;
  #pragma unroll
  for (int rnd = 0; rnd < 4; ++rnd){
    if (w == rnd){
      #pragma unroll
      for (int i = 0; i < 16; ++i){
        int dl = (i & 3) + 8 * (i >> 2) + 4 * lh1;
        if (rnd == 0){
          of[dl][l31]      = wgt * o0[i];
          of[32 + dl][l31] = wgt * o1[i];
          if (dl < 16) of[64 + dl][l31] = wgt * o2[i];
        } else {
          of[dl][l31]      += wgt * o0[i];
          of[32 + dl][l31] += wgt * o1[i];
          if (dl < 16) of[64 + dl][l31] += wgt * o2[i];
        }
      }
    }
    __syncthreads();
  }
  const int tq = threadIdx.x & 31, ds0 = (threadIdx.x >> 5) * 10;
  float Lq = Lsh[tq];
  #pragma unroll
  for (int j = 0; j < 10; ++j)
    ot2[tq][ds0 + j] = f2b(of[ds0 + j][tq] / Lq);
  __syncthreads();
  if (threadIdx.x < 64){
    int qq = threadIdx.x >> 1, half = threadIdx.x & 1;
    #pragma unroll
    for (int j2 = 0; j2 < 20; ++j2){
      unsigned v = *(const unsigned*)&ot2[qq][half * 40 + j2 * 2];
      *(unsigned*)&out[(size_t)(qr + qq) * HID + h * HDIM + half * 40 + j2 * 2] = v;
    }
  }
}

// ---------------- host ----------------------------------------------------
extern "C" void kernel_launch(void* const* d_in, const int* in_sizes, int n_in,
                              void* d_out, int out_size, void* d_ws, size_t ws_size,
                              hipStream_t stream)
{
  const float* hidden = (const float*)d_in[0];
  const float* cosT   = (const float*)d_in[3];
  const float* sinT   = (const float*)d_in[4];
  const float* qkv_w  = (const float*)d_in[5];
  const float* qkv_b  = (const float*)d_in[6];
  const float* proj_w = (const float*)d_in[7];
  const float* proj_b = (const float*)d_in[8];
  const float* norm1_w= (const float*)d_in[9];
  const float* norm2_w= (const float*)d_in[10];
  const float* gate_w = (const float*)d_in[11];
  const float* gate_b = (const float*)d_in[12];
  const float* up_w   = (const float*)d_in[13];
  const float* up_b   = (const float*)d_in[14];
  const float* down_w = (const float*)d_in[15];
  const float* down_b = (const float*)d_in[16];
  const float* ln_q_w = (const float*)d_in[17];
  const float* m0_w   = (const float*)d_in[18];
  const float* m0_b   = (const float*)d_in[19];
  const float* m2_w   = (const float*)d_in[20];
  const float* m2_b   = (const float*)d_in[21];

  char* ws = (char*)d_ws;
  size_t off = 0;
  auto carve = [&](size_t bytes)->char*{
    char* p = ws + off; off += (bytes + 255) & ~(size_t)255; return p;
  };
  unsigned short* x    = (unsigned short*)carve((size_t)S_LEN * HID * 2);
  unsigned short* hbuf = (unsigned short*)carve((size_t)S_LEN * HID * 2);
  unsigned short* qkvb = (unsigned short*)carve((size_t)S_LEN * 3840 * 2);
  unsigned short* qp   = (unsigned short*)carve((size_t)NHEADS * S_LEN * HDP * 2);
  unsigned short* kp   = (unsigned short*)carve((size_t)NHEADS * S_LEN * HDP * 2);
  unsigned short* vtb  = (unsigned short*)carve((size_t)NHEADS * VROWS * S_LEN * 2);
  unsigned short* ao   = (unsigned short*)carve((size_t)S_LEN * HID * 2);
  unsigned short* mlp  = (unsigned short*)carve((size_t)S_LEN * IDIMP * 2);
  unsigned short* mg   = (unsigned short*)carve((size_t)512 * MERGED * 2);
  float*          cbias= (float*)         carve((size_t)LAYERS * 2 * IDIMP * 4);
  (void)ws_size; (void)in_sizes; (void)n_in; (void)out_size;

  concat_bias_kernel<<<dim3(27, LAYERS), 256, 0, stream>>>(gate_b, up_b, cbias);
  h2b_kernel<<<(int)((size_t)S_LEN * HID / 8 / 256), 256, 0, stream>>>(hidden, x);

  for (int i = 0; i < LAYERS; ++i){
    const float* wqkv = qkv_w + (size_t)i * 3840 * HID;
    const float* wproj= proj_w + (size_t)i * HID * HID;
    const float* wgate= gate_w + (size_t)i * IDIM * HID;
    const float* wup  = up_w   + (size_t)i * IDIM * HID;
    const float* wdown= down_w + (size_t)i * HID * IDIM;

    rmsnorm_kernel<<<S_LEN, 256, 0, stream>>>(x, norm1_w + (size_t)i * HID, hbuf, HID);
    gemm_kernel<3,128,128,0><<<dim3(30, 16), 256, 0, stream>>>(
        hbuf, HID, wqkv, nullptr, HID, 3840, HID,
        qkv_b + (size_t)i * 3840, 3840, qkvb, 3840, nullptr, HID);
    if (i == 3 || i == 7){
      rope_split_kernel<<<dim3(NHEADS, 16), 256, 0, stream>>>(qkvb, cosT, sinT, qp, kp, vtb);
      flash_full_kernel<<<dim3(64, 16), 256, 0, stream>>>(qp, kp, vtb, ao);
    } else {
      rope_window_kernel<<<dim3(16, 16), 256, 0, stream>>>(qkvb, cosT, sinT, ao);
    }
    gemm_kernel<1,64,64,0><<<dim3(20, 32), 256, 0, stream>>>(
        ao, HID, wproj, nullptr, HID, HID, HID,
        proj_b + (size_t)i * HID, HID, x, HID, x, HID);
    rmsnorm_kernel<<<S_LEN, 256, 0, stream>>>(x, norm2_w + (size_t)i * HID, hbuf, HID);
    gemm_kernel<4,128,128,1><<<dim3(54, 16), 256, 0, stream>>>(
        hbuf, HID, wgate, wup, HID, IDIM, HID,
        cbias + (size_t)i * 2 * IDIMP, 2 * IDIMP, mlp, IDIMP, nullptr, HID);
    gemm_kernel<1,64,64,0><<<dim3(20, 32), 256, 0, stream>>>(
        mlp, IDIMP, wdown, nullptr, IDIM, HID, IDIM,
        down_b + (size_t)i * HID, HID, x, HID, x, IDIMP);
  }
  // patch merger
  rmsnorm_kernel<<<S_LEN, 256, 0, stream>>>(x, ln_q_w, hbuf, HID);
  gemm_kernel<2,64,64,0><<<dim3(80, 8), 256, 0, stream>>>(
      hbuf, MERGED, m0_w, nullptr, MERGED, MERGED, MERGED,
      m0_b, MERGED, mg, MERGED, nullptr, MERGED);
  gemm_kernel<0,64,64,0><<<dim3(56, 8), 256, 0, stream>>>(
      mg, MERGED, m2_w, nullptr, MERGED, OUTD, MERGED,
      m2_b, OUTD, d_out, OUTD, nullptr, MERGED);
}

// Round 17
// 2313.863 us; speedup vs baseline: 1.2714x; 1.2714x over previous
//
#include <hip/hip_runtime.h>
#include <hip/hip_bf16.h>
#include <math.h>

#define S_LEN 2048
#define HID   1280
#define NHEADS 16
#define HDIM  80
#define HDP   96
#define VROWS 96
#define LAYERS 8
#define IDIM  3420
#define IDIMP 3456
#define MERGED 5120
#define OUTD  3584
#define LWE   19824640LL

typedef __attribute__((ext_vector_type(8))) short short8;
typedef __attribute__((ext_vector_type(4))) float f32x4;
typedef __attribute__((ext_vector_type(16))) float f32x16;
typedef unsigned int u32;
typedef __attribute__((ext_vector_type(4))) u32 u32x4;
typedef __attribute__((address_space(1))) const u32* gptr_t;
typedef __attribute__((address_space(3))) u32* lptr_t;

__device__ inline unsigned short f2b(float f){
  __hip_bfloat16 b = __float2bfloat16(f);
  return __builtin_bit_cast(unsigned short, b);
}
__device__ inline float b2f(unsigned short u){
  return __bfloat162float(__builtin_bit_cast(__hip_bfloat16, u));
}
__device__ inline unsigned pk2(float lo, float hi){
  return (unsigned)f2b(lo) | ((unsigned)f2b(hi) << 16);
}

// ---------------- all-weights convert f32 -> bf16 (4 split dispatches) ----
#define NSEG 42
struct ConvSegs {
  int bpre[NSEG + 1];
  long long srcoff[NSEG];
  long long dstoff[NSEG];
  int srcbase[NSEG];
  int N[NSEG], K[NSEG], Kp[NSEG];
  int rstride[NSEG], roffs[NSEG];
};

__global__ __launch_bounds__(256) void convert_all_kernel(
    ConvSegs cs, int bstart,
    const float* __restrict__ b0, const float* __restrict__ b1,
    const float* __restrict__ b2, const float* __restrict__ b3,
    const float* __restrict__ b4, const float* __restrict__ b5,
    const float* __restrict__ b6,
    unsigned short* __restrict__ dst)
{
  const int b = blockIdx.x + bstart;
  int seg = 0;
  while (seg < NSEG - 1 && cs.bpre[seg + 1] <= b) ++seg;
  const int Kp = cs.Kp[seg], K = cs.K[seg], N = cs.N[seg];
  const int kg = Kp >> 3;
  size_t g = (size_t)(b - cs.bpre[seg]) * 256 + threadIdx.x;
  int k8 = (int)(g % kg);
  int n  = (int)(g / kg);
  int k0 = k8 * 8;
  const float* base;
  switch (cs.srcbase[seg]){
    case 0: base = b0; break; case 1: base = b1; break;
    case 2: base = b2; break; case 3: base = b3; break;
    case 4: base = b4; break; case 5: base = b5; break;
    default: base = b6; break;
  }
  const float* src = base + cs.srcoff[seg];
  u32 out0, out1, out2, out3;
  if (n < N && k0 + 8 <= K){
    const float* s = src + (size_t)n * K + k0;
    f32x4 f0 = __builtin_nontemporal_load((const f32x4*)s);
    f32x4 f1 = __builtin_nontemporal_load((const f32x4*)(s + 4));
    out0 = pk2(f0[0], f0[1]); out1 = pk2(f0[2], f0[3]);
    out2 = pk2(f1[0], f1[1]); out3 = pk2(f1[2], f1[3]);
  } else {
    u32 tmp[4];
    #pragma unroll
    for (int j = 0; j < 4; ++j){
      int ka = k0 + 2 * j;
      float lv = (n < N && ka     < K) ? src[(size_t)n * K + ka]     : 0.f;
      float hv = (n < N && ka + 1 < K) ? src[(size_t)n * K + ka + 1] : 0.f;
      tmp[j] = pk2(lv, hv);
    }
    out0 = tmp[0]; out1 = tmp[1]; out2 = tmp[2]; out3 = tmp[3];
  }
  size_t de = (size_t)cs.dstoff[seg] +
              ((size_t)n * cs.rstride[seg] + cs.roffs[seg]) * Kp + k0;
  u32x4 ov = {out0, out1, out2, out3};
  __builtin_nontemporal_store(ov, (u32x4*)(dst + de));
}

// hidden f32 -> bf16 residual stream
__global__ __launch_bounds__(256) void h2b_kernel(
    const float* __restrict__ in, unsigned short* __restrict__ out)
{
  size_t i = ((size_t)blockIdx.x * 256 + threadIdx.x) * 8;
  f32x4 a = *(const f32x4*)(in + i);
  f32x4 b = *(const f32x4*)(in + i + 4);
  u32x4 o = {pk2(a[0], a[1]), pk2(a[2], a[3]), pk2(b[0], b[1]), pk2(b[2], b[3])};
  *(u32x4*)(out + i) = o;
}

// interleaved bias: even = gate, odd = up
__global__ __launch_bounds__(256) void concat_bias_kernel(
    const float* __restrict__ g, const float* __restrict__ u, float* __restrict__ o)
{
  int L = blockIdx.y;
  int n = blockIdx.x * 256 + threadIdx.x;
  if (n >= 2 * IDIMP) return;
  int c = n >> 1, which = n & 1;
  float v = 0.f;
  if (c < IDIM) v = which ? u[(size_t)L * IDIM + c] : g[(size_t)L * IDIM + c];
  o[(size_t)L * 2 * IDIMP + n] = v;
}

// ---------------- RMSNorm: bf16 in -> bf16 out (vectorized) ---------------
__global__ __launch_bounds__(256) void rmsnorm_kernel(
    const unsigned short* __restrict__ x, const float* __restrict__ w,
    unsigned short* __restrict__ out, int H)
{
  int s = blockIdx.x;
  const unsigned short* row = x + (size_t)s * H;
  const int c8 = threadIdx.x;
  const bool act = c8 < (H >> 3);
  float vals[8];
  float ss = 0.f;
  if (act){
    short8 v8 = *(const short8*)(row + c8 * 8);
    #pragma unroll
    for (int j = 0; j < 8; ++j){ vals[j] = b2f((unsigned short)v8[j]); ss += vals[j] * vals[j]; }
  }
  #pragma unroll
  for (int off = 32; off >= 1; off >>= 1) ss += __shfl_xor(ss, off, 64);
  __shared__ float red[4];
  if ((threadIdx.x & 63) == 0) red[threadIdx.x >> 6] = ss;
  __syncthreads();
  ss = red[0] + red[1] + red[2] + red[3];
  float rs = rsqrtf(ss / H + 1e-6f);
  if (act){
    f32x4 w0 = *(const f32x4*)(w + c8 * 8);
    f32x4 w1 = *(const f32x4*)(w + c8 * 8 + 4);
    u32x4 o = {pk2(vals[0] * rs * w0[0], vals[1] * rs * w0[1]),
               pk2(vals[2] * rs * w0[2], vals[3] * rs * w0[3]),
               pk2(vals[4] * rs * w1[0], vals[5] * rs * w1[1]),
               pk2(vals[6] * rs * w1[2], vals[7] * rs * w1[3])};
    *(u32x4*)(out + (size_t)s * H + c8 * 8) = o;
  }
}

// ---------------- bf16 MFMA GEMM, 32x32x16 fragments, BMxBN templated ------
// EPI 0: f32 = acc+bias   1: bf16 = b2f(res)+acc+bias (res bf16, may alias)
// EPI 2: bf16 = gelu(acc+bias)   3: bf16 = acc+bias   4: bf16 silu-mul
template<int EPI, int BM, int BN>
__global__ __launch_bounds__(256) void gemm_kernel(
    const unsigned short* __restrict__ A, int lda,
    const unsigned short* __restrict__ B, int ldb,
    const float* __restrict__ bias, int Nact,
    void* __restrict__ Cv, int ldc,
    const void* __restrict__ res,
    int K)
{
  constexpr int MI = BM / 64;       // 32x32 frags per wave (wave tile BM/2 x BN/2)
  constexpr int NI = BN / 64;
  __shared__ __align__(16) unsigned short As[2][BM * 32];
  __shared__ __align__(16) unsigned short Bs[2][BN * 32];
  const int tid  = threadIdx.x;
  const int lane = tid & 63;
  const int wave = tid >> 6;
  const int wm = wave >> 1, wn = wave & 1;
  const int gx = gridDim.x, gy = gridDim.y;
  const int total = gx * gy;
  const int orig = blockIdx.y * gx + blockIdx.x;
  const int q8 = total >> 3, r8 = total & 7;
  const int xcd = orig & 7, loc = orig >> 3;
  const int wg = (xcd < r8 ? xcd * (q8 + 1) : r8 * (q8 + 1) + (xcd - r8) * q8) + loc;
  const int m0 = (wg % gy) * BM, n0 = (wg / gy) * BN;
  const int l31 = lane & 31, lh1 = lane >> 5;
  const int lrow = lane >> 2;
  const int lcol = lane & 3;
  f32x16 acc[MI][NI] = {};

  auto stage = [&](int bufi, int k0){
    #pragma unroll
    for (int j = 0; j < BM / 64; ++j){
      int chunk = wave * (BM / 64) + j;
      int row  = chunk * 16 + lrow;
      int slot = lcol ^ ((row >> 1) & 3);
      const unsigned short* srcA = A + (size_t)(m0 + row) * lda + k0 + slot * 8;
      __builtin_amdgcn_global_load_lds((gptr_t)srcA, (lptr_t)&As[bufi][chunk * 512], 16, 0, 0);
    }
    #pragma unroll
    for (int j = 0; j < BN / 64; ++j){
      int chunk = wave * (BN / 64) + j;
      int row  = chunk * 16 + lrow;
      int slot = lcol ^ ((row >> 1) & 3);
      const unsigned short* srcB = B + (size_t)(n0 + row) * ldb + k0 + slot * 8;
      __builtin_amdgcn_global_load_lds((gptr_t)srcB, (lptr_t)&Bs[bufi][chunk * 512], 16, 0, 0);
    }
  };

  const int nt = K >> 5;
  stage(0, 0);
  __syncthreads();
  int buf = 0;
  for (int t = 0; t < nt; ++t){
    if (t + 1 < nt) stage(buf ^ 1, (t + 1) << 5);
    short8 af[MI][2], bfr[NI][2];
    #pragma unroll
    for (int mi = 0; mi < MI; ++mi){
      int r = wm * (BM / 2) + mi * 32 + l31;
      int sw = (r >> 1) & 3;
      #pragma unroll
      for (int ks = 0; ks < 2; ++ks){
        int sl = (ks * 2 + lh1) ^ sw;
        af[mi][ks] = *(const short8*)&As[buf][r * 32 + sl * 8];
      }
    }
    #pragma unroll
    for (int ni = 0; ni < NI; ++ni){
      int r = wn * (BN / 2) + ni * 32 + l31;
      int sw = (r >> 1) & 3;
      #pragma unroll
      for (int ks = 0; ks < 2; ++ks){
        int sl = (ks * 2 + lh1) ^ sw;
        bfr[ni][ks] = *(const short8*)&Bs[buf][r * 32 + sl * 8];
      }
    }
    #pragma unroll
    for (int mi = 0; mi < MI; ++mi)
      #pragma unroll
      for (int ni = 0; ni < NI; ++ni)
        #pragma unroll
        for (int ks = 0; ks < 2; ++ks)
          acc[mi][ni] = __builtin_amdgcn_mfma_f32_32x32x16_bf16(
              af[mi][ks], bfr[ni][ks], acc[mi][ni], 0, 0, 0);
    __syncthreads();
    buf ^= 1;
  }

  // C/D 32x32 layout: col = l31, row = (r&3) + 8*(r>>2) + 4*lh1
  #pragma unroll
  for (int mi = 0; mi < MI; ++mi){
    int mrow0 = m0 + wm * (BM / 2) + mi * 32 + 4 * lh1;
    #pragma unroll
    for (int ni = 0; ni < NI; ++ni){
      int gn = n0 + wn * (BN / 2) + ni * 32 + l31;
      float bv = (gn < Nact) ? bias[gn] : 0.f;
      #pragma unroll
      for (int r = 0; r < 16; ++r){
        int row = mrow0 + (r & 3) + 8 * (r >> 2);
        float v = acc[mi][ni][r] + bv;
        if (EPI == 4){
          float partner = __shfl_xor(v, 1);
          if (!(l31 & 1)){
            float rr = v / (1.f + __expf(-v)) * partner;   // silu(gate)*up
            ((unsigned short*)Cv)[(size_t)row * ldc + (gn >> 1)] = f2b(rr);
          }
        } else {
          size_t offc = (size_t)row * ldc + gn;
          if (EPI == 0)      ((float*)Cv)[offc] = v;
          else if (EPI == 1) ((unsigned short*)Cv)[offc] =
                                f2b(v + b2f(((const unsigned short*)res)[offc]));
          else if (EPI == 2) ((unsigned short*)Cv)[offc] = f2b(0.5f * v * (1.0f + erff(v * 0.70710678118f)));
          else               ((unsigned short*)Cv)[offc] = f2b(v);
        }
      }
    }
  }
}

// ---------------- RoPE + QKV split to global (full-attn layers only) ------
__global__ __launch_bounds__(256) void rope_split_kernel(
    const unsigned short* __restrict__ qkv, const float* __restrict__ cosT,
    const float* __restrict__ sinT,
    unsigned short* __restrict__ qo, unsigned short* __restrict__ ko,
    unsigned short* __restrict__ vt)
{
  __shared__ unsigned short vtile[80][128];
  int id = blockIdx.y * 16 + blockIdx.x;
  int logical = ((id & 7) << 5) + (id >> 3);
  const int h = logical & 15;
  const int s0 = (logical >> 4) * 128;
  const int t = threadIdx.x;
  const int sr = t >> 1, half = t & 1;
  const int s = s0 + sr;
  const unsigned short* row = qkv + (size_t)s * 3840 + h * 80;
  const float* crow = cosT + (size_t)s * 80;
  const float* srow = sinT + (size_t)s * 80;
  const float sgn = half ? 1.f : -1.f;
  #pragma unroll
  for (int g = 0; g < 5; ++g){
    int d  = half * 40 + g * 8;
    int dp = 40 - half * 40 + g * 8;
    short8 q8  = *(const short8*)(row + d);
    short8 k8  = *(const short8*)(row + 1280 + d);
    short8 qp8 = *(const short8*)(row + dp);
    short8 kp8 = *(const short8*)(row + 1280 + dp);
    short8 v8  = *(const short8*)(row + 2560 + d);
    f32x4 c0  = *(const f32x4*)(crow + d);
    f32x4 c1  = *(const f32x4*)(crow + d + 4);
    f32x4 sn0 = *(const f32x4*)(srow + d);
    f32x4 sn1 = *(const f32x4*)(srow + d + 4);
    float cc[8] = {c0[0], c0[1], c0[2], c0[3], c1[0], c1[1], c1[2], c1[3]};
    float ss[8] = {sn0[0], sn0[1], sn0[2], sn0[3], sn1[0], sn1[1], sn1[2], sn1[3]};
    short8 qo8, ko8;
    #pragma unroll
    for (int j = 0; j < 8; ++j){
      float qv = b2f((unsigned short)q8[j]);
      float kv = b2f((unsigned short)k8[j]);
      float qr = sgn * b2f((unsigned short)qp8[j]);
      float kr = sgn * b2f((unsigned short)kp8[j]);
      qo8[j] = (short)f2b(qv * cc[j] + qr * ss[j]);
      ko8[j] = (short)f2b(kv * cc[j] + kr * ss[j]);
      vtile[d + j][sr] = (unsigned short)v8[j];
    }
    size_t qkoff = ((size_t)h * S_LEN + s) * HDP + d;
    *(short8*)(qo + qkoff) = qo8;
    *(short8*)(ko + qkoff) = ko8;
  }
  {
    short8 z = {};
    size_t poff = ((size_t)h * S_LEN + s) * HDP + 80 + half * 8;
    *(short8*)(qo + poff) = z;
    *(short8*)(ko + poff) = z;
  }
  __syncthreads();
  #pragma unroll
  for (int it = 0; it < 5; ++it){
    int j = t + it * 256;
    int d = j >> 4, ch = j & 15;
    u32x4 v = *(const u32x4*)&vtile[d][ch * 8];
    *(u32x4*)(vt + ((size_t)h * VROWS + d) * S_LEN + s0 + ch * 8) = v;
  }
}

// ---------------- FUSED RoPE + windowed flash (6 of 8 layers) --------------
#define QKPAD 104
#define VPAD  136
__global__ __launch_bounds__(256) void rope_window_kernel(
    const unsigned short* __restrict__ qkv, const float* __restrict__ cosT,
    const float* __restrict__ sinT, unsigned short* __restrict__ out)
{
  __shared__ __align__(16) unsigned short qs[128][QKPAD];   // reused as ot
  __shared__ __align__(16) unsigned short ks[128][QKPAD];
  __shared__ __align__(16) unsigned short vtile[96][VPAD];
  unsigned short (*ot)[32][88] = (unsigned short(*)[32][88])&qs[0][0];
  int id = blockIdx.y * 16 + blockIdx.x;
  int logical = ((id & 7) << 5) + (id >> 3);
  const int h = logical & 15;
  const int s0 = (logical >> 4) * 128;
  const int t = threadIdx.x;
  {
    const int sr = t >> 1, half = t & 1;
    const int s = s0 + sr;
    const unsigned short* row = qkv + (size_t)s * 3840 + h * 80;
    const float* crow = cosT + (size_t)s * 80;
    const float* srow = sinT + (size_t)s * 80;
    const float sgn = half ? 1.f : -1.f;
    #pragma unroll
    for (int g = 0; g < 5; ++g){
      int d  = half * 40 + g * 8;
      int dp = 40 - half * 40 + g * 8;
      short8 q8  = *(const short8*)(row + d);
      short8 k8  = *(const short8*)(row + 1280 + d);
      short8 qp8 = *(const short8*)(row + dp);
      short8 kp8 = *(const short8*)(row + 1280 + dp);
      short8 v8  = *(const short8*)(row + 2560 + d);
      f32x4 c0  = *(const f32x4*)(crow + d);
      f32x4 c1  = *(const f32x4*)(crow + d + 4);
      f32x4 sn0 = *(const f32x4*)(srow + d);
      f32x4 sn1 = *(const f32x4*)(srow + d + 4);
      float cc[8] = {c0[0], c0[1], c0[2], c0[3], c1[0], c1[1], c1[2], c1[3]};
      float ss[8] = {sn0[0], sn0[1], sn0[2], sn0[3], sn1[0], sn1[1], sn1[2], sn1[3]};
      short8 qo8, ko8;
      #pragma unroll
      for (int j = 0; j < 8; ++j){
        float qv = b2f((unsigned short)q8[j]);
        float kv = b2f((unsigned short)k8[j]);
        float qr = sgn * b2f((unsigned short)qp8[j]);
        float kr = sgn * b2f((unsigned short)kp8[j]);
        qo8[j] = (short)f2b(qv * cc[j] + qr * ss[j]);
        ko8[j] = (short)f2b(kv * cc[j] + kr * ss[j]);
        vtile[d + j][sr] = (unsigned short)v8[j];
      }
      *(short8*)&qs[sr][d] = qo8;
      *(short8*)&ks[sr][d] = ko8;
    }
    short8 z = {};
    *(short8*)&qs[sr][80 + half * 8] = z;
    *(short8*)&ks[sr][80 + half * 8] = z;
    #pragma unroll
    for (int r9 = 0; r9 < 2; ++r9){
      int task = t + r9 * 256;
      if (task < 16 * 17){
        int rr = task / 17, cc2 = (task % 17) * 8;
        *(short8*)&vtile[80 + rr][cc2] = z;
      }
    }
  }
  __syncthreads();

  const int lane = t & 63;
  const int w = t >> 6;
  const int l31 = lane & 31, lh1 = lane >> 5;
  const int qrl = w * 32;
  const int kv0 = (w >> 1) * 64;

  short8 qa[5];
  #pragma unroll
  for (int kc = 0; kc < 5; ++kc)
    qa[kc] = *(const short8*)&qs[qrl + l31][kc * 16 + lh1 * 8];
  __syncthreads();

  float m_ = -1e30f, l_ = 0.f;
  f32x16 o0 = {}, o1 = {}, o2 = {};
  const float scale = 0.11180339887498949f;

  #pragma unroll
  for (int step = 0; step < 2; ++step){
    int kvl = kv0 + step * 32;
    f32x16 sc = {};
    __builtin_amdgcn_s_setprio(1);
    #pragma unroll
    for (int kc = 0; kc < 5; ++kc){
      short8 kf = *(const short8*)&ks[kvl + l31][kc * 16 + lh1 * 8];
      sc = __builtin_amdgcn_mfma_f32_32x32x16_bf16(kf, qa[kc], sc, 0, 0, 0);
    }
    __builtin_amdgcn_s_setprio(0);
    float tmax = sc[0];
    #pragma unroll
    for (int i = 1; i < 16; ++i) tmax = fmaxf(tmax, sc[i]);
    tmax = fmaxf(tmax, __shfl_xor(tmax, 32)) * scale;
    if (!__all(tmax <= m_ + 8.f)){
      float mnew = fmaxf(m_, tmax);
      float corr = __expf(m_ - mnew);
      l_ *= corr;
      #pragma unroll
      for (int i = 0; i < 16; ++i){ o0[i] *= corr; o1[i] *= corr; o2[i] *= corr; }
      m_ = mnew;
    }
    float p[16];
    float rs = 0.f;
    #pragma unroll
    for (int i = 0; i < 16; ++i){ p[i] = __expf(sc[i] * scale - m_); rs += p[i]; }
    rs += __shfl_xor(rs, 32);
    l_ += rs;
    unsigned wd0[4], wd1[4];
    #pragma unroll
    for (int j = 0; j < 2; ++j){
      unsigned Aj = pk2(p[2 * j],     p[2 * j + 1]);
      unsigned Bj = pk2(p[4 + 2 * j], p[4 + 2 * j + 1]);
      unsigned t0 = __shfl_xor(Aj, 32);
      unsigned t1 = __shfl_xor(Bj, 32);
      wd0[j]     = lh1 ? t1 : Aj;
      wd0[2 + j] = lh1 ? Bj : t0;
      Aj = pk2(p[8 + 2 * j],  p[8 + 2 * j + 1]);
      Bj = pk2(p[12 + 2 * j], p[12 + 2 * j + 1]);
      t0 = __shfl_xor(Aj, 32);
      t1 = __shfl_xor(Bj, 32);
      wd1[j]     = lh1 ? t1 : Aj;
      wd1[2 + j] = lh1 ? Bj : t0;
    }
    __builtin_amdgcn_s_setprio(1);
    #pragma unroll
    for (int kc2 = 0; kc2 < 2; ++kc2){
      u32x4 uw = kc2 ? u32x4{wd1[0], wd1[1], wd1[2], wd1[3]}
                     : u32x4{wd0[0], wd0[1], wd0[2], wd0[3]};
      short8 pb = __builtin_bit_cast(short8, uw);
      int sv = kvl + kc2 * 16 + lh1 * 8;
      o0 = __builtin_amdgcn_mfma_f32_32x32x16_bf16(
          *(const short8*)&vtile[l31][sv],      pb, o0, 0, 0, 0);
      o1 = __builtin_amdgcn_mfma_f32_32x32x16_bf16(
          *(const short8*)&vtile[32 + l31][sv], pb, o1, 0, 0, 0);
      o2 = __builtin_amdgcn_mfma_f32_32x32x16_bf16(
          *(const short8*)&vtile[64 + l31][sv], pb, o2, 0, 0, 0);
    }
    __builtin_amdgcn_s_setprio(0);
  }

  float inv = 1.f / l_;
  #pragma unroll
  for (int r = 0; r < 16; ++r){
    int dl = (r & 3) + 8 * (r >> 2) + 4 * lh1;
    ot[w][l31][dl]      = f2b(o0[r] * inv);
    ot[w][l31][32 + dl] = f2b(o1[r] * inv);
    if (dl < 16) ot[w][l31][64 + dl] = f2b(o2[r] * inv);
  }
  int qq = lane >> 1, half2 = lane & 1;
  #pragma unroll
  for (int j = 0; j < 20; ++j){
    unsigned v = *(const unsigned*)&ot[w][qq][half2 * 40 + j * 2];
    *(unsigned*)&out[(size_t)(s0 + qrl + qq) * HID + h * HDIM + half2 * 40 + j * 2] = v;
  }
}

// ---------------- Flash attention for FULL layers (split-kv in-block) ------
__global__ __launch_bounds__(256) void flash_full_kernel(
    const unsigned short* __restrict__ q, const unsigned short* __restrict__ k,
    const unsigned short* __restrict__ vt, unsigned short* __restrict__ out)
{
  const int lane = threadIdx.x & 63;
  const int w = threadIdx.x >> 6;
  const int l31 = lane & 31, lh1 = lane >> 5;
  int id = blockIdx.y * gridDim.x + blockIdx.x;
  int logical = ((id & 7) << 7) + (id >> 3);
  const int h = logical >> 6;
  const int qr = (logical & 63) * 32;
  const unsigned short* qh = q + (size_t)h * S_LEN * HDP;
  const unsigned short* kh = k + (size_t)h * S_LEN * HDP;
  const unsigned short* vh = vt + (size_t)h * VROWS * S_LEN;

  short8 qa[5];
  #pragma unroll
  for (int kc = 0; kc < 5; ++kc)
    qa[kc] = *(const short8*)(qh + (size_t)(qr + l31) * HDP + kc * 16 + lh1 * 8);

  float m_ = -1e30f, l_ = 0.f;
  f32x16 o0 = {}, o1 = {}, o2 = {};
  const float scale = 0.11180339887498949f;

  for (int kvt = w * 512; kvt < w * 512 + 512; kvt += 32){
    f32x16 sc = {};
    __builtin_amdgcn_s_setprio(1);
    #pragma unroll
    for (int kc = 0; kc < 5; ++kc){
      short8 kf = *(const short8*)(kh + (size_t)(kvt + l31) * HDP + kc * 16 + lh1 * 8);
      sc = __builtin_amdgcn_mfma_f32_32x32x16_bf16(kf, qa[kc], sc, 0, 0, 0);
    }
    __builtin_amdgcn_s_setprio(0);
    float t = sc[0];
    #pragma unroll
    for (int i = 1; i < 16; ++i) t = fmaxf(t, sc[i]);
    t = fmaxf(t, __shfl_xor(t, 32)) * scale;
    if (!__all(t <= m_ + 8.f)){
      float mnew = fmaxf(m_, t);
      float corr = __expf(m_ - mnew);
      l_ *= corr;
      #pragma unroll
      for (int i = 0; i < 16; ++i){ o0[i] *= corr; o1[i] *= corr; o2[i] *= corr; }
      m_ = mnew;
    }
    float p[16];
    float rs = 0.f;
    #pragma unroll
    for (int i = 0; i < 16; ++i){ p[i] = __expf(sc[i] * scale - m_); rs += p[i]; }
    rs += __shfl_xor(rs, 32);
    l_ += rs;
    unsigned wd0[4], wd1[4];
    #pragma unroll
    for (int j = 0; j < 2; ++j){
      unsigned Aj = pk2(p[2 * j],     p[2 * j + 1]);
      unsigned Bj = pk2(p[4 + 2 * j], p[4 + 2 * j + 1]);
      unsigned t0 = __shfl_xor(Aj, 32);
      unsigned t1 = __shfl_xor(Bj, 32);
      wd0[j]     = lh1 ? t1 : Aj;
      wd0[2 + j] = lh1 ? Bj : t0;
      Aj = pk2(p[8 + 2 * j],  p[8 + 2 * j + 1]);
      Bj = pk2(p[12 + 2 * j], p[12 + 2 * j + 1]);
      t0 = __shfl_xor(Aj, 32);
      t1 = __shfl_xor(Bj, 32);
      wd1[j]     = lh1 ? t1 : Aj;
      wd1[2 + j] = lh1 ? Bj : t0;
    }
    __builtin_amdgcn_s_setprio(1);
    #pragma unroll
    for (int kc2 = 0; kc2 < 2; ++kc2){
      u32x4 uw = kc2 ? u32x4{wd1[0], wd1[1], wd1[2], wd1[3]}
                     : u32x4{wd0[0], wd0[1], wd0[2], wd0[3]};
      short8 pb = __builtin_bit_cast(short8, uw);
      const unsigned short* vb = vh + kvt + kc2 * 16 + lh1 * 8;
      o0 = __builtin_amdgcn_mfma_f32_32x32x16_bf16(
          *(const short8*)(vb + (size_t)(l31)      * S_LEN), pb, o0, 0, 0, 0);
      o1 = __builtin_amdgcn_mfma_f32_32x32x16_bf16(
          *(const short8*)(vb + (size_t)(32 + l31) * S_LEN), pb, o1, 0, 0, 0);
      o2 = __builtin_amdgcn_mfma_f32_32x32x16_bf16(
          *(const short8*)(vb + (size_t)(64 + l31) * S_LEN), pb, o2, 0, 0, 0);
    }
    __builtin_amdgcn_s_setprio(0);
  }

  __shared__ float of[80][33];
  __shared__ float mlsh[4][32][2];
  __shared__ float Lsh[32];
  __shared__ unsigned short ot2[32][88];
  if (lane < 32){ mlsh[w][l31][0] = m_; mlsh[w][l31][1] = l_; }
  __syncthreads();
  float M = fmaxf(fmaxf(mlsh[0][l31][0], mlsh[1][l31][0]),
                  fmaxf(mlsh[2][l31][0], mlsh[3][l31][0]));
  float L = 0.f;
  #pragma unroll
  for (int c = 0; c < 4; ++c) L += __expf(mlsh[c][l31][0] - M) * mlsh[c][l31][1];
  float wgt = __expf(m_ - M);
  if (w == 0 && lane < 32) Lsh[l31] = L;
  #pragma unroll
  for (int rnd = 0; rnd < 4; ++rnd){
    if (w == rnd){
      #pragma unroll
      for (int i = 0; i < 16; ++i){
        int dl = (i & 3) + 8 * (i >> 2) + 4 * lh1;
        if (rnd == 0){
          of[dl][l31]      = wgt * o0[i];
          of[32 + dl][l31] = wgt * o1[i];
          if (dl < 16) of[64 + dl][l31] = wgt * o2[i];
        } else {
          of[dl][l31]      += wgt * o0[i];
          of[32 + dl][l31] += wgt * o1[i];
          if (dl < 16) of[64 + dl][l31] += wgt * o2[i];
        }
      }
    }
    __syncthreads();
  }
  const int tq = threadIdx.x & 31, ds0 = (threadIdx.x >> 5) * 10;
  float Lq = Lsh[tq];
  #pragma unroll
  for (int j = 0; j < 10; ++j)
    ot2[tq][ds0 + j] = f2b(of[ds0 + j][tq] / Lq);
  __syncthreads();
  if (threadIdx.x < 64){
    int qq = threadIdx.x >> 1, half = threadIdx.x & 1;
    #pragma unroll
    for (int j2 = 0; j2 < 20; ++j2){
      unsigned v = *(const unsigned*)&ot2[qq][half * 40 + j2 * 2];
      *(unsigned*)&out[(size_t)(qr + qq) * HID + h * HDIM + half * 40 + j2 * 2] = v;
    }
  }
}

// ---------------- host ----------------------------------------------------
extern "C" void kernel_launch(void* const* d_in, const int* in_sizes, int n_in,
                              void* d_out, int out_size, void* d_ws, size_t ws_size,
                              hipStream_t stream)
{
  const float* hidden = (const float*)d_in[0];
  const float* cosT   = (const float*)d_in[3];
  const float* sinT   = (const float*)d_in[4];
  const float* qkv_w  = (const float*)d_in[5];
  const float* qkv_b  = (const float*)d_in[6];
  const float* proj_w = (const float*)d_in[7];
  const float* proj_b = (const float*)d_in[8];
  const float* norm1_w= (const float*)d_in[9];
  const float* norm2_w= (const float*)d_in[10];
  const float* gate_w = (const float*)d_in[11];
  const float* gate_b = (const float*)d_in[12];
  const float* up_w   = (const float*)d_in[13];
  const float* up_b   = (const float*)d_in[14];
  const float* down_w = (const float*)d_in[15];
  const float* down_b = (const float*)d_in[16];
  const float* ln_q_w = (const float*)d_in[17];
  const float* m0_w   = (const float*)d_in[18];
  const float* m0_b   = (const float*)d_in[19];
  const float* m2_w   = (const float*)d_in[20];
  const float* m2_b   = (const float*)d_in[21];

  char* ws = (char*)d_ws;
  size_t off = 0;
  auto carve = [&](size_t bytes)->char*{
    char* p = ws + off; off += (bytes + 255) & ~(size_t)255; return p;
  };
  unsigned short* x    = (unsigned short*)carve((size_t)S_LEN * HID * 2);
  unsigned short* hbuf = (unsigned short*)carve((size_t)S_LEN * HID * 2);
  unsigned short* qkvb = (unsigned short*)carve((size_t)S_LEN * 3840 * 2);
  unsigned short* qp   = (unsigned short*)carve((size_t)NHEADS * S_LEN * HDP * 2);
  unsigned short* kp   = (unsigned short*)carve((size_t)NHEADS * S_LEN * HDP * 2);
  unsigned short* vtb  = (unsigned short*)carve((size_t)NHEADS * VROWS * S_LEN * 2);
  unsigned short* ao   = (unsigned short*)carve((size_t)S_LEN * HID * 2);
  unsigned short* mlp  = (unsigned short*)carve((size_t)S_LEN * IDIMP * 2);
  unsigned short* mg   = (unsigned short*)carve((size_t)512 * MERGED * 2);
  float*          cbias= (float*)         carve((size_t)LAYERS * 2 * IDIMP * 4);
  unsigned short* wbf  = (unsigned short*)carve((size_t)203161600 * 2);
  (void)ws_size; (void)in_sizes; (void)n_in; (void)out_size;

  ConvSegs cs;
  int totalblocks = 0;
  {
    int si = 0;
    auto add = [&](int base, long long soff, long long doff, int N, int K,
                   int Np, int Kp, int rstride, int roffs){
      cs.bpre[si] = totalblocks;
      cs.srcbase[si] = base; cs.srcoff[si] = soff; cs.dstoff[si] = doff;
      cs.N[si] = N; cs.K[si] = K; cs.Kp[si] = Kp;
      cs.rstride[si] = rstride; cs.roffs[si] = roffs;
      long long groups = (long long)Np * (Kp >> 3);
      totalblocks += (int)((groups + 255) / 256);
      ++si;
    };
    for (long long i = 0; i < LAYERS; ++i){
      add(0, i * 3840LL * HID,        i * LWE + 0,        3840, HID, 3840, HID, 1, 0);
      add(1, i * (long long)HID * HID, i * LWE + 4915200,  HID, HID, HID, HID, 1, 0);
      add(2, i * (long long)IDIM * HID, i * LWE + 6553600,  IDIM, HID, IDIMP, HID, 2, 0);
      add(3, i * (long long)IDIM * HID, i * LWE + 6553600,  IDIM, HID, IDIMP, HID, 2, 1);
      add(4, i * (long long)HID * IDIM, i * LWE + 15400960, HID, IDIM, HID, IDIMP, 1, 0);
    }
    add(5, 0, 8 * LWE,            MERGED, MERGED, MERGED, MERGED, 1, 0);
    add(6, 0, 8 * LWE + 26214400, OUTD,   MERGED, OUTD,   MERGED, 1, 0);
    cs.bpre[NSEG] = totalblocks;
  }

  {
    int chunk = (totalblocks + 3) / 4;
    for (int c = 0; c < 4; ++c){
      int bs = c * chunk;
      int nb = (bs + chunk <= totalblocks) ? chunk : (totalblocks - bs);
      if (nb > 0)
        convert_all_kernel<<<nb, 256, 0, stream>>>(
            cs, bs, qkv_w, proj_w, gate_w, up_w, down_w, m0_w, m2_w, wbf);
    }
  }
  concat_bias_kernel<<<dim3(27, LAYERS), 256, 0, stream>>>(gate_b, up_b, cbias);
  h2b_kernel<<<(int)((size_t)S_LEN * HID / 8 / 256), 256, 0, stream>>>(hidden, x);

  for (int i = 0; i < LAYERS; ++i){
    unsigned short* wl = wbf + (size_t)i * LWE;
    unsigned short* wqkv = wl;
    unsigned short* wproj= wl + 4915200;
    unsigned short* wgu  = wl + 6553600;
    unsigned short* wdown= wl + 15400960;

    rmsnorm_kernel<<<S_LEN, 256, 0, stream>>>(x, norm1_w + (size_t)i * HID, hbuf, HID);
    gemm_kernel<3,128,128><<<dim3(30, 16), 256, 0, stream>>>(
        hbuf, HID, wqkv, HID, qkv_b + (size_t)i * 3840, 3840,
        qkvb, 3840, nullptr, HID);
    if (i == 3 || i == 7){
      rope_split_kernel<<<dim3(NHEADS, 16), 256, 0, stream>>>(qkvb, cosT, sinT, qp, kp, vtb);
      flash_full_kernel<<<dim3(64, 16), 256, 0, stream>>>(qp, kp, vtb, ao);
    } else {
      rope_window_kernel<<<dim3(16, 16), 256, 0, stream>>>(qkvb, cosT, sinT, ao);
    }
    gemm_kernel<1,64,64><<<dim3(20, 32), 256, 0, stream>>>(
        ao, HID, wproj, HID, proj_b + (size_t)i * HID, HID,
        x, HID, x, HID);
    rmsnorm_kernel<<<S_LEN, 256, 0, stream>>>(x, norm2_w + (size_t)i * HID, hbuf, HID);
    gemm_kernel<4,128,128><<<dim3(54, 16), 256, 0, stream>>>(
        hbuf, HID, wgu, HID, cbias + (size_t)i * 2 * IDIMP, 2 * IDIMP,
        mlp, IDIMP, nullptr, HID);
    gemm_kernel<1,64,64><<<dim3(20, 32), 256, 0, stream>>>(
        mlp, IDIMP, wdown, IDIMP, down_b + (size_t)i * HID, HID,
        x, HID, x, IDIMP);
  }
  // patch merger
  unsigned short* wm0 = wbf + 8 * LWE;
  unsigned short* wm2 = wm0 + (size_t)MERGED * MERGED;
  rmsnorm_kernel<<<S_LEN, 256, 0, stream>>>(x, ln_q_w, hbuf, HID);
  gemm_kernel<2,64,64><<<dim3(80, 8), 256, 0, stream>>>(
      hbuf, MERGED, wm0, MERGED, m0_b, MERGED, mg, MERGED, nullptr, MERGED);
  gemm_kernel<0,64,64><<<dim3(56, 8), 256, 0, stream>>>(
      mg, MERGED, wm2, MERGED, m2_b, OUTD, d_out, OUTD, nullptr, MERGED);
}

// Round 18
// 2298.335 us; speedup vs baseline: 1.2800x; 1.0068x over previous
//
#include <hip/hip_runtime.h>
#include <hip/hip_bf16.h>
#include <math.h>

#define S_LEN 2048
#define HID   1280
#define NHEADS 16
#define HDIM  80
#define VROWS 96
#define LAYERS 8
#define IDIM  3420
#define IDIMP 3456
#define MERGED 5120
#define OUTD  3584
#define LWE   19824640LL

typedef __attribute__((ext_vector_type(8))) short short8;
typedef __attribute__((ext_vector_type(4))) float f32x4;
typedef __attribute__((ext_vector_type(16))) float f32x16;
typedef unsigned int u32;
typedef __attribute__((ext_vector_type(4))) u32 u32x4;
typedef __attribute__((address_space(1))) const u32* gptr_t;
typedef __attribute__((address_space(3))) u32* lptr_t;

__device__ inline unsigned short f2b(float f){
  __hip_bfloat16 b = __float2bfloat16(f);
  return __builtin_bit_cast(unsigned short, b);
}
__device__ inline float b2f(unsigned short u){
  return __bfloat162float(__builtin_bit_cast(__hip_bfloat16, u));
}
__device__ inline unsigned pk2(float lo, float hi){
  return (unsigned)f2b(lo) | ((unsigned)f2b(hi) << 16);
}

// ---------------- all-weights convert f32 -> bf16 (one dispatch) ----------
#define NSEG 42
struct ConvSegs {
  int bpre[NSEG + 1];
  long long srcoff[NSEG];
  long long dstoff[NSEG];
  int srcbase[NSEG];
  int N[NSEG], K[NSEG], Kp[NSEG];
  int rstride[NSEG], roffs[NSEG];
};

__global__ __launch_bounds__(256) void convert_all_kernel(
    ConvSegs cs,
    const float* __restrict__ b0, const float* __restrict__ b1,
    const float* __restrict__ b2, const float* __restrict__ b3,
    const float* __restrict__ b4, const float* __restrict__ b5,
    const float* __restrict__ b6,
    unsigned short* __restrict__ dst)
{
  const int b = blockIdx.x;
  int seg = 0;
  while (seg < NSEG - 1 && cs.bpre[seg + 1] <= b) ++seg;
  const int Kp = cs.Kp[seg], K = cs.K[seg], N = cs.N[seg];
  const int kg = Kp >> 3;
  size_t g = (size_t)(b - cs.bpre[seg]) * 256 + threadIdx.x;
  int k8 = (int)(g % kg);
  int n  = (int)(g / kg);
  int k0 = k8 * 8;
  const float* base;
  switch (cs.srcbase[seg]){
    case 0: base = b0; break; case 1: base = b1; break;
    case 2: base = b2; break; case 3: base = b3; break;
    case 4: base = b4; break; case 5: base = b5; break;
    default: base = b6; break;
  }
  const float* src = base + cs.srcoff[seg];
  u32 out0, out1, out2, out3;
  if (n < N && k0 + 8 <= K){
    const float* s = src + (size_t)n * K + k0;
    f32x4 f0 = __builtin_nontemporal_load((const f32x4*)s);
    f32x4 f1 = __builtin_nontemporal_load((const f32x4*)(s + 4));
    out0 = pk2(f0[0], f0[1]); out1 = pk2(f0[2], f0[3]);
    out2 = pk2(f1[0], f1[1]); out3 = pk2(f1[2], f1[3]);
  } else {
    u32 tmp[4];
    #pragma unroll
    for (int j = 0; j < 4; ++j){
      int ka = k0 + 2 * j;
      float lv = (n < N && ka     < K) ? src[(size_t)n * K + ka]     : 0.f;
      float hv = (n < N && ka + 1 < K) ? src[(size_t)n * K + ka + 1] : 0.f;
      tmp[j] = pk2(lv, hv);
    }
    out0 = tmp[0]; out1 = tmp[1]; out2 = tmp[2]; out3 = tmp[3];
  }
  size_t de = (size_t)cs.dstoff[seg] +
              ((size_t)n * cs.rstride[seg] + cs.roffs[seg]) * Kp + k0;
  u32x4 ov = {out0, out1, out2, out3};
  __builtin_nontemporal_store(ov, (u32x4*)(dst + de));
}

// hidden f32 -> bf16 residual stream
__global__ __launch_bounds__(256) void h2b_kernel(
    const float* __restrict__ in, unsigned short* __restrict__ out)
{
  size_t i = ((size_t)blockIdx.x * 256 + threadIdx.x) * 8;
  f32x4 a = *(const f32x4*)(in + i);
  f32x4 b = *(const f32x4*)(in + i + 4);
  u32x4 o = {pk2(a[0], a[1]), pk2(a[2], a[3]), pk2(b[0], b[1]), pk2(b[2], b[3])};
  *(u32x4*)(out + i) = o;
}

// ---------------- RMSNorm: bf16 in -> bf16 out (vectorized) ---------------
__global__ __launch_bounds__(256) void rmsnorm_kernel(
    const unsigned short* __restrict__ x, const float* __restrict__ w,
    unsigned short* __restrict__ out, int H)
{
  int s = blockIdx.x;
  const unsigned short* row = x + (size_t)s * H;
  const int c8 = threadIdx.x;
  const bool act = c8 < (H >> 3);
  float vals[8];
  float ss = 0.f;
  if (act){
    short8 v8 = *(const short8*)(row + c8 * 8);
    #pragma unroll
    for (int j = 0; j < 8; ++j){ vals[j] = b2f((unsigned short)v8[j]); ss += vals[j] * vals[j]; }
  }
  #pragma unroll
  for (int off = 32; off >= 1; off >>= 1) ss += __shfl_xor(ss, off, 64);
  __shared__ float red[4];
  if ((threadIdx.x & 63) == 0) red[threadIdx.x >> 6] = ss;
  __syncthreads();
  ss = red[0] + red[1] + red[2] + red[3];
  float rs = rsqrtf(ss / H + 1e-6f);
  if (act){
    f32x4 w0 = *(const f32x4*)(w + c8 * 8);
    f32x4 w1 = *(const f32x4*)(w + c8 * 8 + 4);
    u32x4 o = {pk2(vals[0] * rs * w0[0], vals[1] * rs * w0[1]),
               pk2(vals[2] * rs * w0[2], vals[3] * rs * w0[3]),
               pk2(vals[4] * rs * w1[0], vals[5] * rs * w1[1]),
               pk2(vals[6] * rs * w1[2], vals[7] * rs * w1[3])};
    *(u32x4*)(out + (size_t)s * H + c8 * 8) = o;
  }
}

// ---------------- bf16 MFMA GEMM, 32x32x16 fragments, BMxBN templated ------
// EPI 0: f32 = acc+bias   1: bf16 = b2f(res)+acc+bias (res bf16, may alias)
// EPI 2: bf16 = gelu(acc+bias)   3: bf16 = acc+bias
// EPI 4: bf16 silu-mul; bias = gate_b, res = up_b (f32), col = gn>>1
template<int EPI, int BM, int BN>
__global__ __launch_bounds__(256) void gemm_kernel(
    const unsigned short* __restrict__ A, int lda,
    const unsigned short* __restrict__ B, int ldb,
    const float* __restrict__ bias, int Nact,
    void* __restrict__ Cv, int ldc,
    const void* __restrict__ res,
    int K)
{
  constexpr int MI = BM / 64;
  constexpr int NI = BN / 64;
  __shared__ __align__(16) unsigned short As[2][BM * 32];
  __shared__ __align__(16) unsigned short Bs[2][BN * 32];
  const int tid  = threadIdx.x;
  const int lane = tid & 63;
  const int wave = tid >> 6;
  const int wm = wave >> 1, wn = wave & 1;
  const int gx = gridDim.x, gy = gridDim.y;
  const int total = gx * gy;
  const int orig = blockIdx.y * gx + blockIdx.x;
  const int q8 = total >> 3, r8 = total & 7;
  const int xcd = orig & 7, loc = orig >> 3;
  const int wg = (xcd < r8 ? xcd * (q8 + 1) : r8 * (q8 + 1) + (xcd - r8) * q8) + loc;
  const int m0 = (wg % gy) * BM, n0 = (wg / gy) * BN;
  const int l31 = lane & 31, lh1 = lane >> 5;
  const int lrow = lane >> 2;
  const int lcol = lane & 3;
  f32x16 acc[MI][NI] = {};

  auto stage = [&](int bufi, int k0){
    #pragma unroll
    for (int j = 0; j < BM / 64; ++j){
      int chunk = wave * (BM / 64) + j;
      int row  = chunk * 16 + lrow;
      int slot = lcol ^ ((row >> 1) & 3);
      const unsigned short* srcA = A + (size_t)(m0 + row) * lda + k0 + slot * 8;
      __builtin_amdgcn_global_load_lds((gptr_t)srcA, (lptr_t)&As[bufi][chunk * 512], 16, 0, 0);
    }
    #pragma unroll
    for (int j = 0; j < BN / 64; ++j){
      int chunk = wave * (BN / 64) + j;
      int row  = chunk * 16 + lrow;
      int slot = lcol ^ ((row >> 1) & 3);
      const unsigned short* srcB = B + (size_t)(n0 + row) * ldb + k0 + slot * 8;
      __builtin_amdgcn_global_load_lds((gptr_t)srcB, (lptr_t)&Bs[bufi][chunk * 512], 16, 0, 0);
    }
  };

  const int nt = K >> 5;
  stage(0, 0);
  __syncthreads();
  int buf = 0;
  for (int t = 0; t < nt; ++t){
    if (t + 1 < nt) stage(buf ^ 1, (t + 1) << 5);
    short8 af[MI][2], bfr[NI][2];
    #pragma unroll
    for (int mi = 0; mi < MI; ++mi){
      int r = wm * (BM / 2) + mi * 32 + l31;
      int sw = (r >> 1) & 3;
      #pragma unroll
      for (int ks = 0; ks < 2; ++ks){
        int sl = (ks * 2 + lh1) ^ sw;
        af[mi][ks] = *(const short8*)&As[buf][r * 32 + sl * 8];
      }
    }
    #pragma unroll
    for (int ni = 0; ni < NI; ++ni){
      int r = wn * (BN / 2) + ni * 32 + l31;
      int sw = (r >> 1) & 3;
      #pragma unroll
      for (int ks = 0; ks < 2; ++ks){
        int sl = (ks * 2 + lh1) ^ sw;
        bfr[ni][ks] = *(const short8*)&Bs[buf][r * 32 + sl * 8];
      }
    }
    #pragma unroll
    for (int mi = 0; mi < MI; ++mi)
      #pragma unroll
      for (int ni = 0; ni < NI; ++ni)
        #pragma unroll
        for (int ks = 0; ks < 2; ++ks)
          acc[mi][ni] = __builtin_amdgcn_mfma_f32_32x32x16_bf16(
              af[mi][ks], bfr[ni][ks], acc[mi][ni], 0, 0, 0);
    __syncthreads();
    buf ^= 1;
  }

  // C/D 32x32 layout: col = l31, row = (r&3) + 8*(r>>2) + 4*lh1
  #pragma unroll
  for (int mi = 0; mi < MI; ++mi){
    int mrow0 = m0 + wm * (BM / 2) + mi * 32 + 4 * lh1;
    #pragma unroll
    for (int ni = 0; ni < NI; ++ni){
      int gn = n0 + wn * (BN / 2) + ni * 32 + l31;
      float bv;
      if (EPI == 4){
        const float* bsel = (l31 & 1) ? (const float*)res : bias;  // up : gate
        bv = (gn < Nact) ? bsel[gn >> 1] : 0.f;
      } else {
        bv = (gn < Nact) ? bias[gn] : 0.f;
      }
      #pragma unroll
      for (int r = 0; r < 16; ++r){
        int row = mrow0 + (r & 3) + 8 * (r >> 2);
        float v = acc[mi][ni][r] + bv;
        if (EPI == 4){
          float partner = __shfl_xor(v, 1);
          if (!(l31 & 1)){
            float rr = v / (1.f + __expf(-v)) * partner;   // silu(gate)*up
            ((unsigned short*)Cv)[(size_t)row * ldc + (gn >> 1)] = f2b(rr);
          }
        } else {
          size_t offc = (size_t)row * ldc + gn;
          if (EPI == 0)      ((float*)Cv)[offc] = v;
          else if (EPI == 1) ((unsigned short*)Cv)[offc] =
                                f2b(v + b2f(((const unsigned short*)res)[offc]));
          else if (EPI == 2) ((unsigned short*)Cv)[offc] = f2b(0.5f * v * (1.0f + erff(v * 0.70710678118f)));
          else               ((unsigned short*)Cv)[offc] = f2b(v);
        }
      }
    }
  }
}

// ---------------- RoPE + QKV split to global (full-attn layers only) ------
// q/k stored at stride HDIM=80 (exactly 5 k-chunks of 16 for 32x32x16).
__global__ __launch_bounds__(256) void rope_split_kernel(
    const unsigned short* __restrict__ qkv, const float* __restrict__ cosT,
    const float* __restrict__ sinT,
    unsigned short* __restrict__ qo, unsigned short* __restrict__ ko,
    unsigned short* __restrict__ vt)
{
  __shared__ unsigned short vtile[80][128];
  int id = blockIdx.y * 16 + blockIdx.x;
  int logical = ((id & 7) << 5) + (id >> 3);
  const int h = logical & 15;
  const int s0 = (logical >> 4) * 128;
  const int t = threadIdx.x;
  const int sr = t >> 1, half = t & 1;
  const int s = s0 + sr;
  const unsigned short* row = qkv + (size_t)s * 3840 + h * 80;
  const float* crow = cosT + (size_t)s * 80;
  const float* srow = sinT + (size_t)s * 80;
  const float sgn = half ? 1.f : -1.f;
  #pragma unroll
  for (int g = 0; g < 5; ++g){
    int d  = half * 40 + g * 8;
    int dp = 40 - half * 40 + g * 8;
    short8 q8  = *(const short8*)(row + d);
    short8 k8  = *(const short8*)(row + 1280 + d);
    short8 qp8 = *(const short8*)(row + dp);
    short8 kp8 = *(const short8*)(row + 1280 + dp);
    short8 v8  = *(const short8*)(row + 2560 + d);
    f32x4 c0  = *(const f32x4*)(crow + d);
    f32x4 c1  = *(const f32x4*)(crow + d + 4);
    f32x4 sn0 = *(const f32x4*)(srow + d);
    f32x4 sn1 = *(const f32x4*)(srow + d + 4);
    float cc[8] = {c0[0], c0[1], c0[2], c0[3], c1[0], c1[1], c1[2], c1[3]};
    float ss[8] = {sn0[0], sn0[1], sn0[2], sn0[3], sn1[0], sn1[1], sn1[2], sn1[3]};
    short8 qo8, ko8;
    #pragma unroll
    for (int j = 0; j < 8; ++j){
      float qv = b2f((unsigned short)q8[j]);
      float kv = b2f((unsigned short)k8[j]);
      float qr = sgn * b2f((unsigned short)qp8[j]);
      float kr = sgn * b2f((unsigned short)kp8[j]);
      qo8[j] = (short)f2b(qv * cc[j] + qr * ss[j]);
      ko8[j] = (short)f2b(kv * cc[j] + kr * ss[j]);
      vtile[d + j][sr] = (unsigned short)v8[j];
    }
    size_t qkoff = ((size_t)h * S_LEN + s) * HDIM + d;
    *(short8*)(qo + qkoff) = qo8;
    *(short8*)(ko + qkoff) = ko8;
  }
  __syncthreads();
  #pragma unroll
  for (int it = 0; it < 5; ++it){
    int j = t + it * 256;
    int d = j >> 4, ch = j & 15;
    u32x4 v = *(const u32x4*)&vtile[d][ch * 8];
    *(u32x4*)(vt + ((size_t)h * VROWS + d) * S_LEN + s0 + ch * 8) = v;
  }
}

// ---------------- FUSED RoPE + windowed flash (6 of 8 layers) --------------
// (LDS pad rows/cols feed only never-stored MFMA outputs -> no zeroing.)
#define QKPAD 104
#define VPAD  136
__global__ __launch_bounds__(256) void rope_window_kernel(
    const unsigned short* __restrict__ qkv, const float* __restrict__ cosT,
    const float* __restrict__ sinT, unsigned short* __restrict__ out)
{
  __shared__ __align__(16) unsigned short qs[128][QKPAD];   // reused as ot
  __shared__ __align__(16) unsigned short ks[128][QKPAD];
  __shared__ __align__(16) unsigned short vtile[96][VPAD];
  unsigned short (*ot)[32][88] = (unsigned short(*)[32][88])&qs[0][0];
  int id = blockIdx.y * 16 + blockIdx.x;
  int logical = ((id & 7) << 5) + (id >> 3);
  const int h = logical & 15;
  const int s0 = (logical >> 4) * 128;
  const int t = threadIdx.x;
  {
    const int sr = t >> 1, half = t & 1;
    const int s = s0 + sr;
    const unsigned short* row = qkv + (size_t)s * 3840 + h * 80;
    const float* crow = cosT + (size_t)s * 80;
    const float* srow = sinT + (size_t)s * 80;
    const float sgn = half ? 1.f : -1.f;
    #pragma unroll
    for (int g = 0; g < 5; ++g){
      int d  = half * 40 + g * 8;
      int dp = 40 - half * 40 + g * 8;
      short8 q8  = *(const short8*)(row + d);
      short8 k8  = *(const short8*)(row + 1280 + d);
      short8 qp8 = *(const short8*)(row + dp);
      short8 kp8 = *(const short8*)(row + 1280 + dp);
      short8 v8  = *(const short8*)(row + 2560 + d);
      f32x4 c0  = *(const f32x4*)(crow + d);
      f32x4 c1  = *(const f32x4*)(crow + d + 4);
      f32x4 sn0 = *(const f32x4*)(srow + d);
      f32x4 sn1 = *(const f32x4*)(srow + d + 4);
      float cc[8] = {c0[0], c0[1], c0[2], c0[3], c1[0], c1[1], c1[2], c1[3]};
      float ss[8] = {sn0[0], sn0[1], sn0[2], sn0[3], sn1[0], sn1[1], sn1[2], sn1[3]};
      short8 qo8, ko8;
      #pragma unroll
      for (int j = 0; j < 8; ++j){
        float qv = b2f((unsigned short)q8[j]);
        float kv = b2f((unsigned short)k8[j]);
        float qr = sgn * b2f((unsigned short)qp8[j]);
        float kr = sgn * b2f((unsigned short)kp8[j]);
        qo8[j] = (short)f2b(qv * cc[j] + qr * ss[j]);
        ko8[j] = (short)f2b(kv * cc[j] + kr * ss[j]);
        vtile[d + j][sr] = (unsigned short)v8[j];
      }
      *(short8*)&qs[sr][d] = qo8;
      *(short8*)&ks[sr][d] = ko8;
    }
  }
  __syncthreads();

  const int lane = t & 63;
  const int w = t >> 6;
  const int l31 = lane & 31, lh1 = lane >> 5;
  const int qrl = w * 32;
  const int kv0 = (w >> 1) * 64;

  short8 qa[5];
  #pragma unroll
  for (int kc = 0; kc < 5; ++kc)
    qa[kc] = *(const short8*)&qs[qrl + l31][kc * 16 + lh1 * 8];
  __syncthreads();

  float m_ = -1e30f, l_ = 0.f;
  f32x16 o0 = {}, o1 = {}, o2 = {};
  const float scale = 0.11180339887498949f;

  #pragma unroll
  for (int step = 0; step < 2; ++step){
    int kvl = kv0 + step * 32;
    f32x16 sc = {};
    __builtin_amdgcn_s_setprio(1);
    #pragma unroll
    for (int kc = 0; kc < 5; ++kc){
      short8 kf = *(const short8*)&ks[kvl + l31][kc * 16 + lh1 * 8];
      sc = __builtin_amdgcn_mfma_f32_32x32x16_bf16(kf, qa[kc], sc, 0, 0, 0);
    }
    __builtin_amdgcn_s_setprio(0);
    float tmax = sc[0];
    #pragma unroll
    for (int i = 1; i < 16; ++i) tmax = fmaxf(tmax, sc[i]);
    tmax = fmaxf(tmax, __shfl_xor(tmax, 32)) * scale;
    if (!__all(tmax <= m_ + 8.f)){
      float mnew = fmaxf(m_, tmax);
      float corr = __expf(m_ - mnew);
      l_ *= corr;
      #pragma unroll
      for (int i = 0; i < 16; ++i){ o0[i] *= corr; o1[i] *= corr; o2[i] *= corr; }
      m_ = mnew;
    }
    float p[16];
    float rs = 0.f;
    #pragma unroll
    for (int i = 0; i < 16; ++i){ p[i] = __expf(sc[i] * scale - m_); rs += p[i]; }
    rs += __shfl_xor(rs, 32);
    l_ += rs;
    unsigned wd0[4], wd1[4];
    #pragma unroll
    for (int j = 0; j < 2; ++j){
      unsigned Aj = pk2(p[2 * j],     p[2 * j + 1]);
      unsigned Bj = pk2(p[4 + 2 * j], p[4 + 2 * j + 1]);
      unsigned t0 = __shfl_xor(Aj, 32);
      unsigned t1 = __shfl_xor(Bj, 32);
      wd0[j]     = lh1 ? t1 : Aj;
      wd0[2 + j] = lh1 ? Bj : t0;
      Aj = pk2(p[8 + 2 * j],  p[8 + 2 * j + 1]);
      Bj = pk2(p[12 + 2 * j], p[12 + 2 * j + 1]);
      t0 = __shfl_xor(Aj, 32);
      t1 = __shfl_xor(Bj, 32);
      wd1[j]     = lh1 ? t1 : Aj;
      wd1[2 + j] = lh1 ? Bj : t0;
    }
    __builtin_amdgcn_s_setprio(1);
    #pragma unroll
    for (int kc2 = 0; kc2 < 2; ++kc2){
      u32x4 uw = kc2 ? u32x4{wd1[0], wd1[1], wd1[2], wd1[3]}
                     : u32x4{wd0[0], wd0[1], wd0[2], wd0[3]};
      short8 pb = __builtin_bit_cast(short8, uw);
      int sv = kvl + kc2 * 16 + lh1 * 8;
      o0 = __builtin_amdgcn_mfma_f32_32x32x16_bf16(
          *(const short8*)&vtile[l31][sv],      pb, o0, 0, 0, 0);
      o1 = __builtin_amdgcn_mfma_f32_32x32x16_bf16(
          *(const short8*)&vtile[32 + l31][sv], pb, o1, 0, 0, 0);
      o2 = __builtin_amdgcn_mfma_f32_32x32x16_bf16(
          *(const short8*)&vtile[64 + l31][sv], pb, o2, 0, 0, 0);
    }
    __builtin_amdgcn_s_setprio(0);
  }

  float inv = 1.f / l_;
  #pragma unroll
  for (int r = 0; r < 16; ++r){
    int dl = (r & 3) + 8 * (r >> 2) + 4 * lh1;
    ot[w][l31][dl]      = f2b(o0[r] * inv);
    ot[w][l31][32 + dl] = f2b(o1[r] * inv);
    if (dl < 16) ot[w][l31][64 + dl] = f2b(o2[r] * inv);
  }
  int qq = lane >> 1, half2 = lane & 1;
  #pragma unroll
  for (int j = 0; j < 20; ++j){
    unsigned v = *(const unsigned*)&ot[w][qq][half2 * 40 + j * 2];
    *(unsigned*)&out[(size_t)(s0 + qrl + qq) * HID + h * HDIM + half2 * 40 + j * 2] = v;
  }
}

// ---------------- Flash attention for FULL layers (split-kv in-block) ------
__global__ __launch_bounds__(256) void flash_full_kernel(
    const unsigned short* __restrict__ q, const unsigned short* __restrict__ k,
    const unsigned short* __restrict__ vt, unsigned short* __restrict__ out)
{
  const int lane = threadIdx.x & 63;
  const int w = threadIdx.x >> 6;
  const int l31 = lane & 31, lh1 = lane >> 5;
  int id = blockIdx.y * gridDim.x + blockIdx.x;
  int logical = ((id & 7) << 7) + (id >> 3);
  const int h = logical >> 6;
  const int qr = (logical & 63) * 32;
  const unsigned short* qh = q + (size_t)h * S_LEN * HDIM;
  const unsigned short* kh = k + (size_t)h * S_LEN * HDIM;
  const unsigned short* vh = vt + (size_t)h * VROWS * S_LEN;

  short8 qa[5];
  #pragma unroll
  for (int kc = 0; kc < 5; ++kc)
    qa[kc] = *(const short8*)(qh + (size_t)(qr + l31) * HDIM + kc * 16 + lh1 * 8);

  float m_ = -1e30f, l_ = 0.f;
  f32x16 o0 = {}, o1 = {}, o2 = {};
  const float scale = 0.11180339887498949f;

  for (int kvt = w * 512; kvt < w * 512 + 512; kvt += 32){
    f32x16 sc = {};
    __builtin_amdgcn_s_setprio(1);
    #pragma unroll
    for (int kc = 0; kc < 5; ++kc){
      short8 kf = *(const short8*)(kh + (size_t)(kvt + l31) * HDIM + kc * 16 + lh1 * 8);
      sc = __builtin_amdgcn_mfma_f32_32x32x16_bf16(kf, qa[kc], sc, 0, 0, 0);
    }
    __builtin_amdgcn_s_setprio(0);
    float t = sc[0];
    #pragma unroll
    for (int i = 1; i < 16; ++i) t = fmaxf(t, sc[i]);
    t = fmaxf(t, __shfl_xor(t, 32)) * scale;
    if (!__all(t <= m_ + 8.f)){
      float mnew = fmaxf(m_, t);
      float corr = __expf(m_ - mnew);
      l_ *= corr;
      #pragma unroll
      for (int i = 0; i < 16; ++i){ o0[i] *= corr; o1[i] *= corr; o2[i] *= corr; }
      m_ = mnew;
    }
    float p[16];
    float rs = 0.f;
    #pragma unroll
    for (int i = 0; i < 16; ++i){ p[i] = __expf(sc[i] * scale - m_); rs += p[i]; }
    rs += __shfl_xor(rs, 32);
    l_ += rs;
    unsigned wd0[4], wd1[4];
    #pragma unroll
    for (int j = 0; j < 2; ++j){
      unsigned Aj = pk2(p[2 * j],     p[2 * j + 1]);
      unsigned Bj = pk2(p[4 + 2 * j], p[4 + 2 * j + 1]);
      unsigned t0 = __shfl_xor(Aj, 32);
      unsigned t1 = __shfl_xor(Bj, 32);
      wd0[j]     = lh1 ? t1 : Aj;
      wd0[2 + j] = lh1 ? Bj : t0;
      Aj = pk2(p[8 + 2 * j],  p[8 + 2 * j + 1]);
      Bj = pk2(p[12 + 2 * j], p[12 + 2 * j + 1]);
      t0 = __shfl_xor(Aj, 32);
      t1 = __shfl_xor(Bj, 32);
      wd1[j]     = lh1 ? t1 : Aj;
      wd1[2 + j] = lh1 ? Bj : t0;
    }
    __builtin_amdgcn_s_setprio(1);
    #pragma unroll
    for (int kc2 = 0; kc2 < 2; ++kc2){
      u32x4 uw = kc2 ? u32x4{wd1[0], wd1[1], wd1[2], wd1[3]}
                     : u32x4{wd0[0], wd0[1], wd0[2], wd0[3]};
      short8 pb = __builtin_bit_cast(short8, uw);
      const unsigned short* vb = vh + kvt + kc2 * 16 + lh1 * 8;
      o0 = __builtin_amdgcn_mfma_f32_32x32x16_bf16(
          *(const short8*)(vb + (size_t)(l31)      * S_LEN), pb, o0, 0, 0, 0);
      o1 = __builtin_amdgcn_mfma_f32_32x32x16_bf16(
          *(const short8*)(vb + (size_t)(32 + l31) * S_LEN), pb, o1, 0, 0, 0);
      o2 = __builtin_amdgcn_mfma_f32_32x32x16_bf16(
          *(const short8*)(vb + (size_t)(64 + l31) * S_LEN), pb, o2, 0, 0, 0);
    }
    __builtin_amdgcn_s_setprio(0);
  }

  __shared__ float of[80][33];
  __shared__ float mlsh[4][32][2];
  __shared__ float Lsh[32];
  __shared__ unsigned short ot2[32][88];
  if (lane < 32){ mlsh[w][l31][0] = m_; mlsh[w][l31][1] = l_; }
  __syncthreads();
  float M = fmaxf(fmaxf(mlsh[0][l31][0], mlsh[1][l31][0]),
                  fmaxf(mlsh[2][l31][0], mlsh[3][l31][0]));
  float L = 0.f;
  #pragma unroll
  for (int c = 0; c < 4; ++c) L += __expf(mlsh[c][l31][0] - M) * mlsh[c][l31][1];
  float wgt = __expf(m_ - M);
  if (w == 0 && lane < 32) Lsh[l31] = L;
  #pragma unroll
  for (int rnd = 0; rnd < 4; ++rnd){
    if (w == rnd){
      #pragma unroll
      for (int i = 0; i < 16; ++i){
        int dl = (i & 3) + 8 * (i >> 2) + 4 * lh1;
        if (rnd == 0){
          of[dl][l31]      = wgt * o0[i];
          of[32 + dl][l31] = wgt * o1[i];
          if (dl < 16) of[64 + dl][l31] = wgt * o2[i];
        } else {
          of[dl][l31]      += wgt * o0[i];
          of[32 + dl][l31] += wgt * o1[i];
          if (dl < 16) of[64 + dl][l31] += wgt * o2[i];
        }
      }
    }
    __syncthreads();
  }
  const int tq = threadIdx.x & 31, ds0 = (threadIdx.x >> 5) * 10;
  float Lq = Lsh[tq];
  #pragma unroll
  for (int j = 0; j < 10; ++j)
    ot2[tq][ds0 + j] = f2b(of[ds0 + j][tq] / Lq);
  __syncthreads();
  if (threadIdx.x < 64){
    int qq = threadIdx.x >> 1, half = threadIdx.x & 1;
    #pragma unroll
    for (int j2 = 0; j2 < 20; ++j2){
      unsigned v = *(const unsigned*)&ot2[qq][half * 40 + j2 * 2];
      *(unsigned*)&out[(size_t)(qr + qq) * HID + h * HDIM + half * 40 + j2 * 2] = v;
    }
  }
}

// ---------------- host ----------------------------------------------------
extern "C" void kernel_launch(void* const* d_in, const int* in_sizes, int n_in,
                              void* d_out, int out_size, void* d_ws, size_t ws_size,
                              hipStream_t stream)
{
  const float* hidden = (const float*)d_in[0];
  const float* cosT   = (const float*)d_in[3];
  const float* sinT   = (const float*)d_in[4];
  const float* qkv_w  = (const float*)d_in[5];
  const float* qkv_b  = (const float*)d_in[6];
  const float* proj_w = (const float*)d_in[7];
  const float* proj_b = (const float*)d_in[8];
  const float* norm1_w= (const float*)d_in[9];
  const float* norm2_w= (const float*)d_in[10];
  const float* gate_w = (const float*)d_in[11];
  const float* gate_b = (const float*)d_in[12];
  const float* up_w   = (const float*)d_in[13];
  const float* up_b   = (const float*)d_in[14];
  const float* down_w = (const float*)d_in[15];
  const float* down_b = (const float*)d_in[16];
  const float* ln_q_w = (const float*)d_in[17];
  const float* m0_w   = (const float*)d_in[18];
  const float* m0_b   = (const float*)d_in[19];
  const float* m2_w   = (const float*)d_in[20];
  const float* m2_b   = (const float*)d_in[21];

  char* ws = (char*)d_ws;
  size_t off = 0;
  auto carve = [&](size_t bytes)->char*{
    char* p = ws + off; off += (bytes + 255) & ~(size_t)255; return p;
  };
  unsigned short* x    = (unsigned short*)carve((size_t)S_LEN * HID * 2);
  unsigned short* hbuf = (unsigned short*)carve((size_t)S_LEN * HID * 2);
  unsigned short* qkvb = (unsigned short*)carve((size_t)S_LEN * 3840 * 2);
  unsigned short* qp   = (unsigned short*)carve((size_t)NHEADS * S_LEN * HDIM * 2);
  unsigned short* kp   = (unsigned short*)carve((size_t)NHEADS * S_LEN * HDIM * 2);
  unsigned short* vtb  = (unsigned short*)carve((size_t)NHEADS * VROWS * S_LEN * 2);
  unsigned short* ao   = (unsigned short*)carve((size_t)S_LEN * HID * 2);
  unsigned short* mlp  = (unsigned short*)carve((size_t)S_LEN * IDIMP * 2);
  unsigned short* mg   = (unsigned short*)carve((size_t)512 * MERGED * 2);
  unsigned short* wbf  = (unsigned short*)carve((size_t)203161600 * 2);
  (void)ws_size; (void)in_sizes; (void)n_in; (void)out_size;

  ConvSegs cs;
  int totalblocks = 0;
  {
    int si = 0;
    auto add = [&](int base, long long soff, long long doff, int N, int K,
                   int Np, int Kp, int rstride, int roffs){
      cs.bpre[si] = totalblocks;
      cs.srcbase[si] = base; cs.srcoff[si] = soff; cs.dstoff[si] = doff;
      cs.N[si] = N; cs.K[si] = K; cs.Kp[si] = Kp;
      cs.rstride[si] = rstride; cs.roffs[si] = roffs;
      long long groups = (long long)Np * (Kp >> 3);
      totalblocks += (int)((groups + 255) / 256);
      ++si;
    };
    for (long long i = 0; i < LAYERS; ++i){
      add(0, i * 3840LL * HID,        i * LWE + 0,        3840, HID, 3840, HID, 1, 0);
      add(1, i * (long long)HID * HID, i * LWE + 4915200,  HID, HID, HID, HID, 1, 0);
      add(2, i * (long long)IDIM * HID, i * LWE + 6553600,  IDIM, HID, IDIMP, HID, 2, 0);
      add(3, i * (long long)IDIM * HID, i * LWE + 6553600,  IDIM, HID, IDIMP, HID, 2, 1);
      add(4, i * (long long)HID * IDIM, i * LWE + 15400960, HID, IDIM, HID, IDIMP, 1, 0);
    }
    add(5, 0, 8 * LWE,            MERGED, MERGED, MERGED, MERGED, 1, 0);
    add(6, 0, 8 * LWE + 26214400, OUTD,   MERGED, OUTD,   MERGED, 1, 0);
    cs.bpre[NSEG] = totalblocks;
  }

  convert_all_kernel<<<totalblocks, 256, 0, stream>>>(
      cs, qkv_w, proj_w, gate_w, up_w, down_w, m0_w, m2_w, wbf);
  h2b_kernel<<<(int)((size_t)S_LEN * HID / 8 / 256), 256, 0, stream>>>(hidden, x);

  for (int i = 0; i < LAYERS; ++i){
    unsigned short* wl = wbf + (size_t)i * LWE;
    unsigned short* wqkv = wl;
    unsigned short* wproj= wl + 4915200;
    unsigned short* wgu  = wl + 6553600;
    unsigned short* wdown= wl + 15400960;

    rmsnorm_kernel<<<S_LEN, 256, 0, stream>>>(x, norm1_w + (size_t)i * HID, hbuf, HID);
    gemm_kernel<3,128,128><<<dim3(30, 16), 256, 0, stream>>>(
        hbuf, HID, wqkv, HID, qkv_b + (size_t)i * 3840, 3840,
        qkvb, 3840, nullptr, HID);
    if (i == 3 || i == 7){
      rope_split_kernel<<<dim3(NHEADS, 16), 256, 0, stream>>>(qkvb, cosT, sinT, qp, kp, vtb);
      flash_full_kernel<<<dim3(64, 16), 256, 0, stream>>>(qp, kp, vtb, ao);
    } else {
      rope_window_kernel<<<dim3(16, 16), 256, 0, stream>>>(qkvb, cosT, sinT, ao);
    }
    gemm_kernel<1,64,64><<<dim3(20, 32), 256, 0, stream>>>(
        ao, HID, wproj, HID, proj_b + (size_t)i * HID, HID,
        x, HID, x, HID);
    rmsnorm_kernel<<<S_LEN, 256, 0, stream>>>(x, norm2_w + (size_t)i * HID, hbuf, HID);
    gemm_kernel<4,128,128><<<dim3(54, 16), 256, 0, stream>>>(
        hbuf, HID, wgu, HID, gate_b + (size_t)i * IDIM, 2 * IDIM,
        mlp, IDIMP, up_b + (size_t)i * IDIM, HID);
    gemm_kernel<1,64,64><<<dim3(20, 32), 256, 0, stream>>>(
        mlp, IDIMP, wdown, IDIMP, down_b + (size_t)i * HID, HID,
        x, HID, x, IDIMP);
  }
  // patch merger
  unsigned short* wm0 = wbf + 8 * LWE;
  unsigned short* wm2 = wm0 + (size_t)MERGED * MERGED;
  rmsnorm_kernel<<<S_LEN, 256, 0, stream>>>(x, ln_q_w, hbuf, HID);
  gemm_kernel<2,64,64><<<dim3(80, 8), 256, 0, stream>>>(
      hbuf, MERGED, wm0, MERGED, m0_b, MERGED, mg, MERGED, nullptr, MERGED);
  gemm_kernel<0,64,64><<<dim3(56, 8), 256, 0, stream>>>(
      mg, MERGED, wm2, MERGED, m2_b, OUTD, d_out, OUTD, nullptr, MERGED);
}

// Round 19
// 2254.410 us; speedup vs baseline: 1.3049x; 1.0195x over previous
//
#include <hip/hip_runtime.h>
#include <hip/hip_bf16.h>
#include <math.h>

#define S_LEN 2048
#define HID   1280
#define NHEADS 16
#define HDIM  80
#define VROWS 96
#define LAYERS 8
#define IDIM  3420
#define IDIMP 3456
#define MERGED 5120
#define OUTD  3584
#define LWE   19824640LL

typedef __attribute__((ext_vector_type(8))) short short8;
typedef __attribute__((ext_vector_type(4))) float f32x4;
typedef __attribute__((ext_vector_type(16))) float f32x16;
typedef unsigned int u32;
typedef __attribute__((ext_vector_type(4))) u32 u32x4;
typedef __attribute__((address_space(1))) const u32* gptr_t;
typedef __attribute__((address_space(3))) u32* lptr_t;

__device__ inline unsigned short f2b(float f){
  __hip_bfloat16 b = __float2bfloat16(f);
  return __builtin_bit_cast(unsigned short, b);
}
__device__ inline float b2f(unsigned short u){
  return __bfloat162float(__builtin_bit_cast(__hip_bfloat16, u));
}
__device__ inline unsigned pk2(float lo, float hi){
  return (unsigned)f2b(lo) | ((unsigned)f2b(hi) << 16);
}

// ---------------- all-weights convert f32 -> bf16 (2 split dispatches) ----
#define NSEG 42
struct ConvSegs {
  int bpre[NSEG + 1];
  long long srcoff[NSEG];
  long long dstoff[NSEG];
  int srcbase[NSEG];
  int N[NSEG], K[NSEG], Kp[NSEG];
  int rstride[NSEG], roffs[NSEG];
};

__global__ __launch_bounds__(256) void convert_all_kernel(
    ConvSegs cs, int bstart,
    const float* __restrict__ b0, const float* __restrict__ b1,
    const float* __restrict__ b2, const float* __restrict__ b3,
    const float* __restrict__ b4, const float* __restrict__ b5,
    const float* __restrict__ b6,
    unsigned short* __restrict__ dst)
{
  const int b = blockIdx.x + bstart;
  int seg = 0;
  while (seg < NSEG - 1 && cs.bpre[seg + 1] <= b) ++seg;
  const int Kp = cs.Kp[seg], K = cs.K[seg], N = cs.N[seg];
  const int kg = Kp >> 3;
  size_t g = (size_t)(b - cs.bpre[seg]) * 256 + threadIdx.x;
  int k8 = (int)(g % kg);
  int n  = (int)(g / kg);
  int k0 = k8 * 8;
  const float* base;
  switch (cs.srcbase[seg]){
    case 0: base = b0; break; case 1: base = b1; break;
    case 2: base = b2; break; case 3: base = b3; break;
    case 4: base = b4; break; case 5: base = b5; break;
    default: base = b6; break;
  }
  const float* src = base + cs.srcoff[seg];
  u32 out0, out1, out2, out3;
  if (n < N && k0 + 8 <= K){
    const float* s = src + (size_t)n * K + k0;
    f32x4 f0 = __builtin_nontemporal_load((const f32x4*)s);
    f32x4 f1 = __builtin_nontemporal_load((const f32x4*)(s + 4));
    out0 = pk2(f0[0], f0[1]); out1 = pk2(f0[2], f0[3]);
    out2 = pk2(f1[0], f1[1]); out3 = pk2(f1[2], f1[3]);
  } else {
    u32 tmp[4];
    #pragma unroll
    for (int j = 0; j < 4; ++j){
      int ka = k0 + 2 * j;
      float lv = (n < N && ka     < K) ? src[(size_t)n * K + ka]     : 0.f;
      float hv = (n < N && ka + 1 < K) ? src[(size_t)n * K + ka + 1] : 0.f;
      tmp[j] = pk2(lv, hv);
    }
    out0 = tmp[0]; out1 = tmp[1]; out2 = tmp[2]; out3 = tmp[3];
  }
  size_t de = (size_t)cs.dstoff[seg] +
              ((size_t)n * cs.rstride[seg] + cs.roffs[seg]) * Kp + k0;
  u32x4 ov = {out0, out1, out2, out3};
  __builtin_nontemporal_store(ov, (u32x4*)(dst + de));
}

// hidden f32 -> bf16 residual stream
__global__ __launch_bounds__(256) void h2b_kernel(
    const float* __restrict__ in, unsigned short* __restrict__ out)
{
  size_t i = ((size_t)blockIdx.x * 256 + threadIdx.x) * 8;
  f32x4 a = *(const f32x4*)(in + i);
  f32x4 b = *(const f32x4*)(in + i + 4);
  u32x4 o = {pk2(a[0], a[1]), pk2(a[2], a[3]), pk2(b[0], b[1]), pk2(b[2], b[3])};
  *(u32x4*)(out + i) = o;
}

// ---------------- RMSNorm: bf16 in -> bf16 out (vectorized) ---------------
__global__ __launch_bounds__(256) void rmsnorm_kernel(
    const unsigned short* __restrict__ x, const float* __restrict__ w,
    unsigned short* __restrict__ out, int H)
{
  int s = blockIdx.x;
  const unsigned short* row = x + (size_t)s * H;
  const int c8 = threadIdx.x;
  const bool act = c8 < (H >> 3);
  float vals[8];
  float ss = 0.f;
  if (act){
    short8 v8 = *(const short8*)(row + c8 * 8);
    #pragma unroll
    for (int j = 0; j < 8; ++j){ vals[j] = b2f((unsigned short)v8[j]); ss += vals[j] * vals[j]; }
  }
  #pragma unroll
  for (int off = 32; off >= 1; off >>= 1) ss += __shfl_xor(ss, off, 64);
  __shared__ float red[4];
  if ((threadIdx.x & 63) == 0) red[threadIdx.x >> 6] = ss;
  __syncthreads();
  ss = red[0] + red[1] + red[2] + red[3];
  float rs = rsqrtf(ss / H + 1e-6f);
  if (act){
    f32x4 w0 = *(const f32x4*)(w + c8 * 8);
    f32x4 w1 = *(const f32x4*)(w + c8 * 8 + 4);
    u32x4 o = {pk2(vals[0] * rs * w0[0], vals[1] * rs * w0[1]),
               pk2(vals[2] * rs * w0[2], vals[3] * rs * w0[3]),
               pk2(vals[4] * rs * w1[0], vals[5] * rs * w1[1]),
               pk2(vals[6] * rs * w1[2], vals[7] * rs * w1[3])};
    *(u32x4*)(out + (size_t)s * H + c8 * 8) = o;
  }
}

// ---------------- bf16 MFMA GEMM, 32x32x16 frags, BM/BN/BK templated -------
// EPI 0: f32 = acc+bias   1: bf16 = b2f(res)+acc+bias (res bf16, may alias)
// EPI 2: bf16 = gelu(acc+bias)   3: bf16 = acc+bias
// EPI 4: bf16 silu-mul; bias = gate_b, res = up_b (f32), col = gn>>1
template<int EPI, int BM, int BN, int BK>
__global__ __launch_bounds__(256) void gemm_kernel(
    const unsigned short* __restrict__ A, int lda,
    const unsigned short* __restrict__ B, int ldb,
    const float* __restrict__ bias, int Nact,
    void* __restrict__ Cv, int ldc,
    const void* __restrict__ res,
    int K)
{
  constexpr int MI = BM / 64;
  constexpr int NI = BN / 64;
  constexpr int KS = BK / 16;            // k-chunks of 16 per K-step
  constexpr int RPC = 512 / BK;          // rows per (wave,call) stage
  constexpr int SWM = BK / 8 - 1;        // swizzle mask over 16B slots
  __shared__ __align__(16) unsigned short As[2][BM * BK];
  __shared__ __align__(16) unsigned short Bs[2][BN * BK];
  const int tid  = threadIdx.x;
  const int lane = tid & 63;
  const int wave = tid >> 6;
  const int wm = wave >> 1, wn = wave & 1;
  const int gx = gridDim.x, gy = gridDim.y;
  const int total = gx * gy;
  const int orig = blockIdx.y * gx + blockIdx.x;
  const int q8 = total >> 3, r8 = total & 7;
  const int xcd = orig & 7, loc = orig >> 3;
  const int wg = (xcd < r8 ? xcd * (q8 + 1) : r8 * (q8 + 1) + (xcd - r8) * q8) + loc;
  const int m0 = (wg % gy) * BM, n0 = (wg / gy) * BN;
  const int l31 = lane & 31, lh1 = lane >> 5;
  const int lrow = lane / (BK / 8);
  const int lcol = lane & (BK / 8 - 1);
  f32x16 acc[MI][NI] = {};

  auto stage = [&](int bufi, int k0){
    #pragma unroll
    for (int j = 0; j < BM * BK / 2048; ++j){
      int chunk = wave * (BM * BK / 2048) + j;
      int row  = chunk * RPC + lrow;
      int slot = lcol ^ ((row >> 1) & SWM);
      const unsigned short* srcA = A + (size_t)(m0 + row) * lda + k0 + slot * 8;
      __builtin_amdgcn_global_load_lds((gptr_t)srcA, (lptr_t)&As[bufi][chunk * 512], 16, 0, 0);
    }
    #pragma unroll
    for (int j = 0; j < BN * BK / 2048; ++j){
      int chunk = wave * (BN * BK / 2048) + j;
      int row  = chunk * RPC + lrow;
      int slot = lcol ^ ((row >> 1) & SWM);
      const unsigned short* srcB = B + (size_t)(n0 + row) * ldb + k0 + slot * 8;
      __builtin_amdgcn_global_load_lds((gptr_t)srcB, (lptr_t)&Bs[bufi][chunk * 512], 16, 0, 0);
    }
  };

  const int nt = K / BK;
  stage(0, 0);
  __syncthreads();
  int buf = 0;
  for (int t = 0; t < nt; ++t){
    if (t + 1 < nt) stage(buf ^ 1, (t + 1) * BK);
    short8 af[MI][KS], bfr[NI][KS];
    #pragma unroll
    for (int mi = 0; mi < MI; ++mi){
      int r = wm * (BM / 2) + mi * 32 + l31;
      int sw = (r >> 1) & SWM;
      #pragma unroll
      for (int ks = 0; ks < KS; ++ks){
        int sl = (ks * 2 + lh1) ^ sw;
        af[mi][ks] = *(const short8*)&As[buf][r * BK + sl * 8];
      }
    }
    #pragma unroll
    for (int ni = 0; ni < NI; ++ni){
      int r = wn * (BN / 2) + ni * 32 + l31;
      int sw = (r >> 1) & SWM;
      #pragma unroll
      for (int ks = 0; ks < KS; ++ks){
        int sl = (ks * 2 + lh1) ^ sw;
        bfr[ni][ks] = *(const short8*)&Bs[buf][r * BK + sl * 8];
      }
    }
    #pragma unroll
    for (int mi = 0; mi < MI; ++mi)
      #pragma unroll
      for (int ni = 0; ni < NI; ++ni)
        #pragma unroll
        for (int ks = 0; ks < KS; ++ks)
          acc[mi][ni] = __builtin_amdgcn_mfma_f32_32x32x16_bf16(
              af[mi][ks], bfr[ni][ks], acc[mi][ni], 0, 0, 0);
    __syncthreads();
    buf ^= 1;
  }

  // C/D 32x32 layout: col = l31, row = (r&3) + 8*(r>>2) + 4*lh1
  #pragma unroll
  for (int mi = 0; mi < MI; ++mi){
    int mrow0 = m0 + wm * (BM / 2) + mi * 32 + 4 * lh1;
    #pragma unroll
    for (int ni = 0; ni < NI; ++ni){
      int gn = n0 + wn * (BN / 2) + ni * 32 + l31;
      float bv;
      if (EPI == 4){
        const float* bsel = (l31 & 1) ? (const float*)res : bias;  // up : gate
        bv = (gn < Nact) ? bsel[gn >> 1] : 0.f;
      } else {
        bv = (gn < Nact) ? bias[gn] : 0.f;
      }
      #pragma unroll
      for (int r = 0; r < 16; ++r){
        int row = mrow0 + (r & 3) + 8 * (r >> 2);
        float v = acc[mi][ni][r] + bv;
        if (EPI == 4){
          float partner = __shfl_xor(v, 1);
          if (!(l31 & 1)){
            float rr = v / (1.f + __expf(-v)) * partner;   // silu(gate)*up
            ((unsigned short*)Cv)[(size_t)row * ldc + (gn >> 1)] = f2b(rr);
          }
        } else {
          size_t offc = (size_t)row * ldc + gn;
          if (EPI == 0)      ((float*)Cv)[offc] = v;
          else if (EPI == 1) ((unsigned short*)Cv)[offc] =
                                f2b(v + b2f(((const unsigned short*)res)[offc]));
          else if (EPI == 2) ((unsigned short*)Cv)[offc] = f2b(0.5f * v * (1.0f + erff(v * 0.70710678118f)));
          else               ((unsigned short*)Cv)[offc] = f2b(v);
        }
      }
    }
  }
}

// ---------------- RoPE + QKV split to global (full-attn layers only) ------
__global__ __launch_bounds__(256) void rope_split_kernel(
    const unsigned short* __restrict__ qkv, const float* __restrict__ cosT,
    const float* __restrict__ sinT,
    unsigned short* __restrict__ qo, unsigned short* __restrict__ ko,
    unsigned short* __restrict__ vt)
{
  __shared__ unsigned short vtile[80][128];
  int id = blockIdx.y * 16 + blockIdx.x;
  int logical = ((id & 7) << 5) + (id >> 3);
  const int h = logical & 15;
  const int s0 = (logical >> 4) * 128;
  const int t = threadIdx.x;
  const int sr = t >> 1, half = t & 1;
  const int s = s0 + sr;
  const unsigned short* row = qkv + (size_t)s * 3840 + h * 80;
  const float* crow = cosT + (size_t)s * 80;
  const float* srow = sinT + (size_t)s * 80;
  const float sgn = half ? 1.f : -1.f;
  #pragma unroll
  for (int g = 0; g < 5; ++g){
    int d  = half * 40 + g * 8;
    int dp = 40 - half * 40 + g * 8;
    short8 q8  = *(const short8*)(row + d);
    short8 k8  = *(const short8*)(row + 1280 + d);
    short8 qp8 = *(const short8*)(row + dp);
    short8 kp8 = *(const short8*)(row + 1280 + dp);
    short8 v8  = *(const short8*)(row + 2560 + d);
    f32x4 c0  = *(const f32x4*)(crow + d);
    f32x4 c1  = *(const f32x4*)(crow + d + 4);
    f32x4 sn0 = *(const f32x4*)(srow + d);
    f32x4 sn1 = *(const f32x4*)(srow + d + 4);
    float cc[8] = {c0[0], c0[1], c0[2], c0[3], c1[0], c1[1], c1[2], c1[3]};
    float ss[8] = {sn0[0], sn0[1], sn0[2], sn0[3], sn1[0], sn1[1], sn1[2], sn1[3]};
    short8 qo8, ko8;
    #pragma unroll
    for (int j = 0; j < 8; ++j){
      float qv = b2f((unsigned short)q8[j]);
      float kv = b2f((unsigned short)k8[j]);
      float qr = sgn * b2f((unsigned short)qp8[j]);
      float kr = sgn * b2f((unsigned short)kp8[j]);
      qo8[j] = (short)f2b(qv * cc[j] + qr * ss[j]);
      ko8[j] = (short)f2b(kv * cc[j] + kr * ss[j]);
      vtile[d + j][sr] = (unsigned short)v8[j];
    }
    size_t qkoff = ((size_t)h * S_LEN + s) * HDIM + d;
    *(short8*)(qo + qkoff) = qo8;
    *(short8*)(ko + qkoff) = ko8;
  }
  __syncthreads();
  #pragma unroll
  for (int it = 0; it < 5; ++it){
    int j = t + it * 256;
    int d = j >> 4, ch = j & 15;
    u32x4 v = *(const u32x4*)&vtile[d][ch * 8];
    *(u32x4*)(vt + ((size_t)h * VROWS + d) * S_LEN + s0 + ch * 8) = v;
  }
}

// ---------------- FUSED RoPE + windowed flash (6 of 8 layers) --------------
#define QKPAD 104
#define VPAD  136
__global__ __launch_bounds__(256) void rope_window_kernel(
    const unsigned short* __restrict__ qkv, const float* __restrict__ cosT,
    const float* __restrict__ sinT, unsigned short* __restrict__ out)
{
  __shared__ __align__(16) unsigned short qs[128][QKPAD];   // reused as ot
  __shared__ __align__(16) unsigned short ks[128][QKPAD];
  __shared__ __align__(16) unsigned short vtile[96][VPAD];
  unsigned short (*ot)[32][88] = (unsigned short(*)[32][88])&qs[0][0];
  int id = blockIdx.y * 16 + blockIdx.x;
  int logical = ((id & 7) << 5) + (id >> 3);
  const int h = logical & 15;
  const int s0 = (logical >> 4) * 128;
  const int t = threadIdx.x;
  {
    const int sr = t >> 1, half = t & 1;
    const int s = s0 + sr;
    const unsigned short* row = qkv + (size_t)s * 3840 + h * 80;
    const float* crow = cosT + (size_t)s * 80;
    const float* srow = sinT + (size_t)s * 80;
    const float sgn = half ? 1.f : -1.f;
    #pragma unroll
    for (int g = 0; g < 5; ++g){
      int d  = half * 40 + g * 8;
      int dp = 40 - half * 40 + g * 8;
      short8 q8  = *(const short8*)(row + d);
      short8 k8  = *(const short8*)(row + 1280 + d);
      short8 qp8 = *(const short8*)(row + dp);
      short8 kp8 = *(const short8*)(row + 1280 + dp);
      short8 v8  = *(const short8*)(row + 2560 + d);
      f32x4 c0  = *(const f32x4*)(crow + d);
      f32x4 c1  = *(const f32x4*)(crow + d + 4);
      f32x4 sn0 = *(const f32x4*)(srow + d);
      f32x4 sn1 = *(const f32x4*)(srow + d + 4);
      float cc[8] = {c0[0], c0[1], c0[2], c0[3], c1[0], c1[1], c1[2], c1[3]};
      float ss[8] = {sn0[0], sn0[1], sn0[2], sn0[3], sn1[0], sn1[1], sn1[2], sn1[3]};
      short8 qo8, ko8;
      #pragma unroll
      for (int j = 0; j < 8; ++j){
        float qv = b2f((unsigned short)q8[j]);
        float kv = b2f((unsigned short)k8[j]);
        float qr = sgn * b2f((unsigned short)qp8[j]);
        float kr = sgn * b2f((unsigned short)kp8[j]);
        qo8[j] = (short)f2b(qv * cc[j] + qr * ss[j]);
        ko8[j] = (short)f2b(kv * cc[j] + kr * ss[j]);
        vtile[d + j][sr] = (unsigned short)v8[j];
      }
      *(short8*)&qs[sr][d] = qo8;
      *(short8*)&ks[sr][d] = ko8;
    }
  }
  __syncthreads();

  const int lane = t & 63;
  const int w = t >> 6;
  const int l31 = lane & 31, lh1 = lane >> 5;
  const int qrl = w * 32;
  const int kv0 = (w >> 1) * 64;

  short8 qa[5];
  #pragma unroll
  for (int kc = 0; kc < 5; ++kc)
    qa[kc] = *(const short8*)&qs[qrl + l31][kc * 16 + lh1 * 8];
  __syncthreads();

  float m_ = -1e30f, l_ = 0.f;
  f32x16 o0 = {}, o1 = {}, o2 = {};
  const float scale = 0.11180339887498949f;

  #pragma unroll
  for (int step = 0; step < 2; ++step){
    int kvl = kv0 + step * 32;
    f32x16 sc = {};
    __builtin_amdgcn_s_setprio(1);
    #pragma unroll
    for (int kc = 0; kc < 5; ++kc){
      short8 kf = *(const short8*)&ks[kvl + l31][kc * 16 + lh1 * 8];
      sc = __builtin_amdgcn_mfma_f32_32x32x16_bf16(kf, qa[kc], sc, 0, 0, 0);
    }
    __builtin_amdgcn_s_setprio(0);
    float tmax = sc[0];
    #pragma unroll
    for (int i = 1; i < 16; ++i) tmax = fmaxf(tmax, sc[i]);
    tmax = fmaxf(tmax, __shfl_xor(tmax, 32)) * scale;
    if (!__all(tmax <= m_ + 8.f)){
      float mnew = fmaxf(m_, tmax);
      float corr = __expf(m_ - mnew);
      l_ *= corr;
      #pragma unroll
      for (int i = 0; i < 16; ++i){ o0[i] *= corr; o1[i] *= corr; o2[i] *= corr; }
      m_ = mnew;
    }
    float p[16];
    float rs = 0.f;
    #pragma unroll
    for (int i = 0; i < 16; ++i){ p[i] = __expf(sc[i] * scale - m_); rs += p[i]; }
    rs += __shfl_xor(rs, 32);
    l_ += rs;
    unsigned wd0[4], wd1[4];
    #pragma unroll
    for (int j = 0; j < 2; ++j){
      unsigned Aj = pk2(p[2 * j],     p[2 * j + 1]);
      unsigned Bj = pk2(p[4 + 2 * j], p[4 + 2 * j + 1]);
      unsigned t0 = __shfl_xor(Aj, 32);
      unsigned t1 = __shfl_xor(Bj, 32);
      wd0[j]     = lh1 ? t1 : Aj;
      wd0[2 + j] = lh1 ? Bj : t0;
      Aj = pk2(p[8 + 2 * j],  p[8 + 2 * j + 1]);
      Bj = pk2(p[12 + 2 * j], p[12 + 2 * j + 1]);
      t0 = __shfl_xor(Aj, 32);
      t1 = __shfl_xor(Bj, 32);
      wd1[j]     = lh1 ? t1 : Aj;
      wd1[2 + j] = lh1 ? Bj : t0;
    }
    __builtin_amdgcn_s_setprio(1);
    #pragma unroll
    for (int kc2 = 0; kc2 < 2; ++kc2){
      u32x4 uw = kc2 ? u32x4{wd1[0], wd1[1], wd1[2], wd1[3]}
                     : u32x4{wd0[0], wd0[1], wd0[2], wd0[3]};
      short8 pb = __builtin_bit_cast(short8, uw);
      int sv = kvl + kc2 * 16 + lh1 * 8;
      o0 = __builtin_amdgcn_mfma_f32_32x32x16_bf16(
          *(const short8*)&vtile[l31][sv],      pb, o0, 0, 0, 0);
      o1 = __builtin_amdgcn_mfma_f32_32x32x16_bf16(
          *(const short8*)&vtile[32 + l31][sv], pb, o1, 0, 0, 0);
      o2 = __builtin_amdgcn_mfma_f32_32x32x16_bf16(
          *(const short8*)&vtile[64 + l31][sv], pb, o2, 0, 0, 0);
    }
    __builtin_amdgcn_s_setprio(0);
  }

  float inv = 1.f / l_;
  #pragma unroll
  for (int r = 0; r < 16; ++r){
    int dl = (r & 3) + 8 * (r >> 2) + 4 * lh1;
    ot[w][l31][dl]      = f2b(o0[r] * inv);
    ot[w][l31][32 + dl] = f2b(o1[r] * inv);
    if (dl < 16) ot[w][l31][64 + dl] = f2b(o2[r] * inv);
  }
  int qq = lane >> 1, half2 = lane & 1;
  #pragma unroll
  for (int j = 0; j < 20; ++j){
    unsigned v = *(const unsigned*)&ot[w][qq][half2 * 40 + j * 2];
    *(unsigned*)&out[(size_t)(s0 + qrl + qq) * HID + h * HDIM + half2 * 40 + j * 2] = v;
  }
}

// ---------------- Flash attention for FULL layers (split-kv in-block) ------
__global__ __launch_bounds__(256) void flash_full_kernel(
    const unsigned short* __restrict__ q, const unsigned short* __restrict__ k,
    const unsigned short* __restrict__ vt, unsigned short* __restrict__ out)
{
  const int lane = threadIdx.x & 63;
  const int w = threadIdx.x >> 6;
  const int l31 = lane & 31, lh1 = lane >> 5;
  int id = blockIdx.y * gridDim.x + blockIdx.x;
  int logical = ((id & 7) << 7) + (id >> 3);
  const int h = logical >> 6;
  const int qr = (logical & 63) * 32;
  const unsigned short* qh = q + (size_t)h * S_LEN * HDIM;
  const unsigned short* kh = k + (size_t)h * S_LEN * HDIM;
  const unsigned short* vh = vt + (size_t)h * VROWS * S_LEN;

  short8 qa[5];
  #pragma unroll
  for (int kc = 0; kc < 5; ++kc)
    qa[kc] = *(const short8*)(qh + (size_t)(qr + l31) * HDIM + kc * 16 + lh1 * 8);

  float m_ = -1e30f, l_ = 0.f;
  f32x16 o0 = {}, o1 = {}, o2 = {};
  const float scale = 0.11180339887498949f;

  for (int kvt = w * 512; kvt < w * 512 + 512; kvt += 32){
    f32x16 sc = {};
    __builtin_amdgcn_s_setprio(1);
    #pragma unroll
    for (int kc = 0; kc < 5; ++kc){
      short8 kf = *(const short8*)(kh + (size_t)(kvt + l31) * HDIM + kc * 16 + lh1 * 8);
      sc = __builtin_amdgcn_mfma_f32_32x32x16_bf16(kf, qa[kc], sc, 0, 0, 0);
    }
    __builtin_amdgcn_s_setprio(0);
    float t = sc[0];
    #pragma unroll
    for (int i = 1; i < 16; ++i) t = fmaxf(t, sc[i]);
    t = fmaxf(t, __shfl_xor(t, 32)) * scale;
    if (!__all(t <= m_ + 8.f)){
      float mnew = fmaxf(m_, t);
      float corr = __expf(m_ - mnew);
      l_ *= corr;
      #pragma unroll
      for (int i = 0; i < 16; ++i){ o0[i] *= corr; o1[i] *= corr; o2[i] *= corr; }
      m_ = mnew;
    }
    float p[16];
    float rs = 0.f;
    #pragma unroll
    for (int i = 0; i < 16; ++i){ p[i] = __expf(sc[i] * scale - m_); rs += p[i]; }
    rs += __shfl_xor(rs, 32);
    l_ += rs;
    unsigned wd0[4], wd1[4];
    #pragma unroll
    for (int j = 0; j < 2; ++j){
      unsigned Aj = pk2(p[2 * j],     p[2 * j + 1]);
      unsigned Bj = pk2(p[4 + 2 * j], p[4 + 2 * j + 1]);
      unsigned t0 = __shfl_xor(Aj, 32);
      unsigned t1 = __shfl_xor(Bj, 32);
      wd0[j]     = lh1 ? t1 : Aj;
      wd0[2 + j] = lh1 ? Bj : t0;
      Aj = pk2(p[8 + 2 * j],  p[8 + 2 * j + 1]);
      Bj = pk2(p[12 + 2 * j], p[12 + 2 * j + 1]);
      t0 = __shfl_xor(Aj, 32);
      t1 = __shfl_xor(Bj, 32);
      wd1[j]     = lh1 ? t1 : Aj;
      wd1[2 + j] = lh1 ? Bj : t0;
    }
    __builtin_amdgcn_s_setprio(1);
    #pragma unroll
    for (int kc2 = 0; kc2 < 2; ++kc2){
      u32x4 uw = kc2 ? u32x4{wd1[0], wd1[1], wd1[2], wd1[3]}
                     : u32x4{wd0[0], wd0[1], wd0[2], wd0[3]};
      short8 pb = __builtin_bit_cast(short8, uw);
      const unsigned short* vb = vh + kvt + kc2 * 16 + lh1 * 8;
      o0 = __builtin_amdgcn_mfma_f32_32x32x16_bf16(
          *(const short8*)(vb + (size_t)(l31)      * S_LEN), pb, o0, 0, 0, 0);
      o1 = __builtin_amdgcn_mfma_f32_32x32x16_bf16(
          *(const short8*)(vb + (size_t)(32 + l31) * S_LEN), pb, o1, 0, 0, 0);
      o2 = __builtin_amdgcn_mfma_f32_32x32x16_bf16(
          *(const short8*)(vb + (size_t)(64 + l31) * S_LEN), pb, o2, 0, 0, 0);
    }
    __builtin_amdgcn_s_setprio(0);
  }

  __shared__ float of[80][33];
  __shared__ float mlsh[4][32][2];
  __shared__ float Lsh[32];
  __shared__ unsigned short ot2[32][88];
  if (lane < 32){ mlsh[w][l31][0] = m_; mlsh[w][l31][1] = l_; }
  __syncthreads();
  float M = fmaxf(fmaxf(mlsh[0][l31][0], mlsh[1][l31][0]),
                  fmaxf(mlsh[2][l31][0], mlsh[3][l31][0]));
  float L = 0.f;
  #pragma unroll
  for (int c = 0; c < 4; ++c) L += __expf(mlsh[c][l31][0] - M) * mlsh[c][l31][1];
  float wgt = __expf(m_ - M);
  if (w == 0 && lane < 32) Lsh[l31] = L;
  #pragma unroll
  for (int rnd = 0; rnd < 4; ++rnd){
    if (w == rnd){
      #pragma unroll
      for (int i = 0; i < 16; ++i){
        int dl = (i & 3) + 8 * (i >> 2) + 4 * lh1;
        if (rnd == 0){
          of[dl][l31]      = wgt * o0[i];
          of[32 + dl][l31] = wgt * o1[i];
          if (dl < 16) of[64 + dl][l31] = wgt * o2[i];
        } else {
          of[dl][l31]      += wgt * o0[i];
          of[32 + dl][l31] += wgt * o1[i];
          if (dl < 16) of[64 + dl][l31] += wgt * o2[i];
        }
      }
    }
    __syncthreads();
  }
  const int tq = threadIdx.x & 31, ds0 = (threadIdx.x >> 5) * 10;
  float Lq = Lsh[tq];
  #pragma unroll
  for (int j = 0; j < 10; ++j)
    ot2[tq][ds0 + j] = f2b(of[ds0 + j][tq] / Lq);
  __syncthreads();
  if (threadIdx.x < 64){
    int qq = threadIdx.x >> 1, half = threadIdx.x & 1;
    #pragma unroll
    for (int j2 = 0; j2 < 20; ++j2){
      unsigned v = *(const unsigned*)&ot2[qq][half * 40 + j2 * 2];
      *(unsigned*)&out[(size_t)(qr + qq) * HID + h * HDIM + half * 40 + j2 * 2] = v;
    }
  }
}

// ---------------- host ----------------------------------------------------
extern "C" void kernel_launch(void* const* d_in, const int* in_sizes, int n_in,
                              void* d_out, int out_size, void* d_ws, size_t ws_size,
                              hipStream_t stream)
{
  const float* hidden = (const float*)d_in[0];
  const float* cosT   = (const float*)d_in[3];
  const float* sinT   = (const float*)d_in[4];
  const float* qkv_w  = (const float*)d_in[5];
  const float* qkv_b  = (const float*)d_in[6];
  const float* proj_w = (const float*)d_in[7];
  const float* proj_b = (const float*)d_in[8];
  const float* norm1_w= (const float*)d_in[9];
  const float* norm2_w= (const float*)d_in[10];
  const float* gate_w = (const float*)d_in[11];
  const float* gate_b = (const float*)d_in[12];
  const float* up_w   = (const float*)d_in[13];
  const float* up_b   = (const float*)d_in[14];
  const float* down_w = (const float*)d_in[15];
  const float* down_b = (const float*)d_in[16];
  const float* ln_q_w = (const float*)d_in[17];
  const float* m0_w   = (const float*)d_in[18];
  const float* m0_b   = (const float*)d_in[19];
  const float* m2_w   = (const float*)d_in[20];
  const float* m2_b   = (const float*)d_in[21];

  char* ws = (char*)d_ws;
  size_t off = 0;
  auto carve = [&](size_t bytes)->char*{
    char* p = ws + off; off += (bytes + 255) & ~(size_t)255; return p;
  };
  unsigned short* x    = (unsigned short*)carve((size_t)S_LEN * HID * 2);
  unsigned short* hbuf = (unsigned short*)carve((size_t)S_LEN * HID * 2);
  unsigned short* qkvb = (unsigned short*)carve((size_t)S_LEN * 3840 * 2);
  unsigned short* qp   = (unsigned short*)carve((size_t)NHEADS * S_LEN * HDIM * 2);
  unsigned short* kp   = (unsigned short*)carve((size_t)NHEADS * S_LEN * HDIM * 2);
  unsigned short* vtb  = (unsigned short*)carve((size_t)NHEADS * VROWS * S_LEN * 2);
  unsigned short* ao   = (unsigned short*)carve((size_t)S_LEN * HID * 2);
  unsigned short* mlp  = (unsigned short*)carve((size_t)S_LEN * IDIMP * 2);
  unsigned short* mg   = (unsigned short*)carve((size_t)512 * MERGED * 2);
  unsigned short* wbf  = (unsigned short*)carve((size_t)203161600 * 2);
  (void)ws_size; (void)in_sizes; (void)n_in; (void)out_size;

  ConvSegs cs;
  int totalblocks = 0;
  {
    int si = 0;
    auto add = [&](int base, long long soff, long long doff, int N, int K,
                   int Np, int Kp, int rstride, int roffs){
      cs.bpre[si] = totalblocks;
      cs.srcbase[si] = base; cs.srcoff[si] = soff; cs.dstoff[si] = doff;
      cs.N[si] = N; cs.K[si] = K; cs.Kp[si] = Kp;
      cs.rstride[si] = rstride; cs.roffs[si] = roffs;
      long long groups = (long long)Np * (Kp >> 3);
      totalblocks += (int)((groups + 255) / 256);
      ++si;
    };
    for (long long i = 0; i < LAYERS; ++i){
      add(0, i * 3840LL * HID,        i * LWE + 0,        3840, HID, 3840, HID, 1, 0);
      add(1, i * (long long)HID * HID, i * LWE + 4915200,  HID, HID, HID, HID, 1, 0);
      add(2, i * (long long)IDIM * HID, i * LWE + 6553600,  IDIM, HID, IDIMP, HID, 2, 0);
      add(3, i * (long long)IDIM * HID, i * LWE + 6553600,  IDIM, HID, IDIMP, HID, 2, 1);
      add(4, i * (long long)HID * IDIM, i * LWE + 15400960, HID, IDIM, HID, IDIMP, 1, 0);
    }
    add(5, 0, 8 * LWE,            MERGED, MERGED, MERGED, MERGED, 1, 0);
    add(6, 0, 8 * LWE + 26214400, OUTD,   MERGED, OUTD,   MERGED, 1, 0);
    cs.bpre[NSEG] = totalblocks;
  }

  {
    int chunk = (totalblocks + 1) / 2;
    for (int c = 0; c < 2; ++c){
      int bs = c * chunk;
      int nb = (bs + chunk <= totalblocks) ? chunk : (totalblocks - bs);
      if (nb > 0)
        convert_all_kernel<<<nb, 256, 0, stream>>>(
            cs, bs, qkv_w, proj_w, gate_w, up_w, down_w, m0_w, m2_w, wbf);
    }
  }
  h2b_kernel<<<(int)((size_t)S_LEN * HID / 8 / 256), 256, 0, stream>>>(hidden, x);

  for (int i = 0; i < LAYERS; ++i){
    unsigned short* wl = wbf + (size_t)i * LWE;
    unsigned short* wqkv = wl;
    unsigned short* wproj= wl + 4915200;
    unsigned short* wgu  = wl + 6553600;
    unsigned short* wdown= wl + 15400960;

    rmsnorm_kernel<<<S_LEN, 256, 0, stream>>>(x, norm1_w + (size_t)i * HID, hbuf, HID);
    gemm_kernel<3,128,128,32><<<dim3(30, 16), 256, 0, stream>>>(
        hbuf, HID, wqkv, HID, qkv_b + (size_t)i * 3840, 3840,
        qkvb, 3840, nullptr, HID);
    if (i == 3 || i == 7){
      rope_split_kernel<<<dim3(NHEADS, 16), 256, 0, stream>>>(qkvb, cosT, sinT, qp, kp, vtb);
      flash_full_kernel<<<dim3(64, 16), 256, 0, stream>>>(qp, kp, vtb, ao);
    } else {
      rope_window_kernel<<<dim3(16, 16), 256, 0, stream>>>(qkvb, cosT, sinT, ao);
    }
    gemm_kernel<1,64,64,32><<<dim3(20, 32), 256, 0, stream>>>(
        ao, HID, wproj, HID, proj_b + (size_t)i * HID, HID,
        x, HID, x, HID);
    rmsnorm_kernel<<<S_LEN, 256, 0, stream>>>(x, norm2_w + (size_t)i * HID, hbuf, HID);
    gemm_kernel<4,128,128,32><<<dim3(54, 16), 256, 0, stream>>>(
        hbuf, HID, wgu, HID, gate_b + (size_t)i * IDIM, 2 * IDIM,
        mlp, IDIMP, up_b + (size_t)i * IDIM, HID);
    gemm_kernel<1,64,64,64><<<dim3(20, 32), 256, 0, stream>>>(
        mlp, IDIMP, wdown, IDIMP, down_b + (size_t)i * HID, HID,
        x, HID, x, IDIMP);
  }
  // patch merger
  unsigned short* wm0 = wbf + 8 * LWE;
  unsigned short* wm2 = wm0 + (size_t)MERGED * MERGED;
  rmsnorm_kernel<<<S_LEN, 256, 0, stream>>>(x, ln_q_w, hbuf, HID);
  gemm_kernel<2,64,64,64><<<dim3(80, 8), 256, 0, stream>>>(
      hbuf, MERGED, wm0, MERGED, m0_b, MERGED, mg, MERGED, nullptr, MERGED);
  gemm_kernel<0,64,64,64><<<dim3(56, 8), 256, 0, stream>>>(
      mg, MERGED, wm2, MERGED, m2_b, OUTD, d_out, OUTD, nullptr, MERGED);
}

// Round 20
// 2245.840 us; speedup vs baseline: 1.3099x; 1.0038x over previous
//
#include <hip/hip_runtime.h>
#include <hip/hip_bf16.h>
#include <math.h>

#define S_LEN 2048
#define HID   1280
#define NHEADS 16
#define HDIM  80
#define VROWS 96
#define LAYERS 8
#define IDIM  3420
#define IDIMP 3456
#define MERGED 5120
#define OUTD  3584
#define LWE   19824640LL

typedef __attribute__((ext_vector_type(8))) short short8;
typedef __attribute__((ext_vector_type(4))) float f32x4;
typedef __attribute__((ext_vector_type(16))) float f32x16;
typedef unsigned int u32;
typedef __attribute__((ext_vector_type(4))) u32 u32x4;
typedef __attribute__((address_space(1))) const u32* gptr_t;
typedef __attribute__((address_space(3))) u32* lptr_t;

__device__ inline unsigned short f2b(float f){
  __hip_bfloat16 b = __float2bfloat16(f);
  return __builtin_bit_cast(unsigned short, b);
}
__device__ inline float b2f(unsigned short u){
  return __bfloat162float(__builtin_bit_cast(__hip_bfloat16, u));
}
__device__ inline unsigned pk2(float lo, float hi){
  return (unsigned)f2b(lo) | ((unsigned)f2b(hi) << 16);
}

// ---------------- all-weights convert f32 -> bf16 (2 split dispatches) ----
#define NSEG 42
struct ConvSegs {
  int bpre[NSEG + 1];
  long long srcoff[NSEG];
  long long dstoff[NSEG];
  int srcbase[NSEG];
  int N[NSEG], K[NSEG], Kp[NSEG];
  int rstride[NSEG], roffs[NSEG];
};

__global__ __launch_bounds__(256) void convert_all_kernel(
    ConvSegs cs, int bstart,
    const float* __restrict__ b0, const float* __restrict__ b1,
    const float* __restrict__ b2, const float* __restrict__ b3,
    const float* __restrict__ b4, const float* __restrict__ b5,
    const float* __restrict__ b6,
    unsigned short* __restrict__ dst)
{
  const int b = blockIdx.x + bstart;
  int seg = 0;
  while (seg < NSEG - 1 && cs.bpre[seg + 1] <= b) ++seg;
  const int Kp = cs.Kp[seg], K = cs.K[seg], N = cs.N[seg];
  const int kg = Kp >> 3;
  size_t g = (size_t)(b - cs.bpre[seg]) * 256 + threadIdx.x;
  int k8 = (int)(g % kg);
  int n  = (int)(g / kg);
  int k0 = k8 * 8;
  const float* base;
  switch (cs.srcbase[seg]){
    case 0: base = b0; break; case 1: base = b1; break;
    case 2: base = b2; break; case 3: base = b3; break;
    case 4: base = b4; break; case 5: base = b5; break;
    default: base = b6; break;
  }
  const float* src = base + cs.srcoff[seg];
  u32 out0, out1, out2, out3;
  if (n < N && k0 + 8 <= K){
    const float* s = src + (size_t)n * K + k0;
    f32x4 f0 = __builtin_nontemporal_load((const f32x4*)s);
    f32x4 f1 = __builtin_nontemporal_load((const f32x4*)(s + 4));
    out0 = pk2(f0[0], f0[1]); out1 = pk2(f0[2], f0[3]);
    out2 = pk2(f1[0], f1[1]); out3 = pk2(f1[2], f1[3]);
  } else {
    u32 tmp[4];
    #pragma unroll
    for (int j = 0; j < 4; ++j){
      int ka = k0 + 2 * j;
      float lv = (n < N && ka     < K) ? src[(size_t)n * K + ka]     : 0.f;
      float hv = (n < N && ka + 1 < K) ? src[(size_t)n * K + ka + 1] : 0.f;
      tmp[j] = pk2(lv, hv);
    }
    out0 = tmp[0]; out1 = tmp[1]; out2 = tmp[2]; out3 = tmp[3];
  }
  size_t de = (size_t)cs.dstoff[seg] +
              ((size_t)n * cs.rstride[seg] + cs.roffs[seg]) * Kp + k0;
  u32x4 ov = {out0, out1, out2, out3};
  __builtin_nontemporal_store(ov, (u32x4*)(dst + de));
}

// hidden f32 -> bf16 residual stream
__global__ __launch_bounds__(256) void h2b_kernel(
    const float* __restrict__ in, unsigned short* __restrict__ out)
{
  size_t i = ((size_t)blockIdx.x * 256 + threadIdx.x) * 8;
  f32x4 a = *(const f32x4*)(in + i);
  f32x4 b = *(const f32x4*)(in + i + 4);
  u32x4 o = {pk2(a[0], a[1]), pk2(a[2], a[3]), pk2(b[0], b[1]), pk2(b[2], b[3])};
  *(u32x4*)(out + i) = o;
}

// ---------------- RMSNorm: bf16 in -> bf16 out (vectorized) ---------------
__global__ __launch_bounds__(256) void rmsnorm_kernel(
    const unsigned short* __restrict__ x, const float* __restrict__ w,
    unsigned short* __restrict__ out, int H)
{
  int s = blockIdx.x;
  const unsigned short* row = x + (size_t)s * H;
  const int c8 = threadIdx.x;
  const bool act = c8 < (H >> 3);
  float vals[8];
  float ss = 0.f;
  if (act){
    short8 v8 = *(const short8*)(row + c8 * 8);
    #pragma unroll
    for (int j = 0; j < 8; ++j){ vals[j] = b2f((unsigned short)v8[j]); ss += vals[j] * vals[j]; }
  }
  #pragma unroll
  for (int off = 32; off >= 1; off >>= 1) ss += __shfl_xor(ss, off, 64);
  __shared__ float red[4];
  if ((threadIdx.x & 63) == 0) red[threadIdx.x >> 6] = ss;
  __syncthreads();
  ss = red[0] + red[1] + red[2] + red[3];
  float rs = rsqrtf(ss / H + 1e-6f);
  if (act){
    f32x4 w0 = *(const f32x4*)(w + c8 * 8);
    f32x4 w1 = *(const f32x4*)(w + c8 * 8 + 4);
    u32x4 o = {pk2(vals[0] * rs * w0[0], vals[1] * rs * w0[1]),
               pk2(vals[2] * rs * w0[2], vals[3] * rs * w0[3]),
               pk2(vals[4] * rs * w1[0], vals[5] * rs * w1[1]),
               pk2(vals[6] * rs * w1[2], vals[7] * rs * w1[3])};
    *(u32x4*)(out + (size_t)s * H + c8 * 8) = o;
  }
}

// ---------------- bf16 MFMA GEMM, 32x32x16 frags, BM/BN/BK templated -------
// EPI 0: f32 = acc+bias   1: bf16 = b2f(res)+acc+bias (res bf16, may alias)
// EPI 2: bf16 = gelu(acc+bias)   3: bf16 = acc+bias
// EPI 4: bf16 silu-mul; bias = gate_b, res = up_b (f32), col = gn>>1
template<int EPI, int BM, int BN, int BK>
__global__ __launch_bounds__(256) void gemm_kernel(
    const unsigned short* __restrict__ A, int lda,
    const unsigned short* __restrict__ B, int ldb,
    const float* __restrict__ bias, int Nact,
    void* __restrict__ Cv, int ldc,
    const void* __restrict__ res,
    int K)
{
  constexpr int MI = BM / 64;
  constexpr int NI = BN / 64;
  constexpr int KS = BK / 16;
  constexpr int RPC = 512 / BK;
  constexpr int SWM = BK / 8 - 1;
  __shared__ __align__(16) unsigned short As[2][BM * BK];
  __shared__ __align__(16) unsigned short Bs[2][BN * BK];
  const int tid  = threadIdx.x;
  const int lane = tid & 63;
  const int wave = tid >> 6;
  const int wm = wave >> 1, wn = wave & 1;
  const int gx = gridDim.x, gy = gridDim.y;
  const int total = gx * gy;
  const int orig = blockIdx.y * gx + blockIdx.x;
  const int q8 = total >> 3, r8 = total & 7;
  const int xcd = orig & 7, loc = orig >> 3;
  const int wg = (xcd < r8 ? xcd * (q8 + 1) : r8 * (q8 + 1) + (xcd - r8) * q8) + loc;
  const int m0 = (wg % gy) * BM, n0 = (wg / gy) * BN;
  const int l31 = lane & 31, lh1 = lane >> 5;
  const int lrow = lane / (BK / 8);
  const int lcol = lane & (BK / 8 - 1);
  f32x16 acc[MI][NI] = {};

  auto stage = [&](int bufi, int k0){
    #pragma unroll
    for (int j = 0; j < BM * BK / 2048; ++j){
      int chunk = wave * (BM * BK / 2048) + j;
      int row  = chunk * RPC + lrow;
      int slot = lcol ^ ((row >> 1) & SWM);
      const unsigned short* srcA = A + (size_t)(m0 + row) * lda + k0 + slot * 8;
      __builtin_amdgcn_global_load_lds((gptr_t)srcA, (lptr_t)&As[bufi][chunk * 512], 16, 0, 0);
    }
    #pragma unroll
    for (int j = 0; j < BN * BK / 2048; ++j){
      int chunk = wave * (BN * BK / 2048) + j;
      int row  = chunk * RPC + lrow;
      int slot = lcol ^ ((row >> 1) & SWM);
      const unsigned short* srcB = B + (size_t)(n0 + row) * ldb + k0 + slot * 8;
      __builtin_amdgcn_global_load_lds((gptr_t)srcB, (lptr_t)&Bs[bufi][chunk * 512], 16, 0, 0);
    }
  };

  const int nt = K / BK;
  stage(0, 0);
  __syncthreads();
  int buf = 0;
  for (int t = 0; t < nt; ++t){
    if (t + 1 < nt) stage(buf ^ 1, (t + 1) * BK);
    short8 af[MI][KS], bfr[NI][KS];
    #pragma unroll
    for (int mi = 0; mi < MI; ++mi){
      int r = wm * (BM / 2) + mi * 32 + l31;
      int sw = (r >> 1) & SWM;
      #pragma unroll
      for (int ks = 0; ks < KS; ++ks){
        int sl = (ks * 2 + lh1) ^ sw;
        af[mi][ks] = *(const short8*)&As[buf][r * BK + sl * 8];
      }
    }
    #pragma unroll
    for (int ni = 0; ni < NI; ++ni){
      int r = wn * (BN / 2) + ni * 32 + l31;
      int sw = (r >> 1) & SWM;
      #pragma unroll
      for (int ks = 0; ks < KS; ++ks){
        int sl = (ks * 2 + lh1) ^ sw;
        bfr[ni][ks] = *(const short8*)&Bs[buf][r * BK + sl * 8];
      }
    }
    #pragma unroll
    for (int mi = 0; mi < MI; ++mi)
      #pragma unroll
      for (int ni = 0; ni < NI; ++ni)
        #pragma unroll
        for (int ks = 0; ks < KS; ++ks)
          acc[mi][ni] = __builtin_amdgcn_mfma_f32_32x32x16_bf16(
              af[mi][ks], bfr[ni][ks], acc[mi][ni], 0, 0, 0);
    __syncthreads();
    buf ^= 1;
  }

  // C/D 32x32 layout: col = l31, row = (r&3) + 8*(r>>2) + 4*lh1
  #pragma unroll
  for (int mi = 0; mi < MI; ++mi){
    int mrow0 = m0 + wm * (BM / 2) + mi * 32 + 4 * lh1;
    #pragma unroll
    for (int ni = 0; ni < NI; ++ni){
      int gn = n0 + wn * (BN / 2) + ni * 32 + l31;
      float bv;
      if (EPI == 4){
        const float* bsel = (l31 & 1) ? (const float*)res : bias;  // up : gate
        bv = (gn < Nact) ? bsel[gn >> 1] : 0.f;
      } else {
        bv = (gn < Nact) ? bias[gn] : 0.f;
      }
      #pragma unroll
      for (int r = 0; r < 16; ++r){
        int row = mrow0 + (r & 3) + 8 * (r >> 2);
        float v = acc[mi][ni][r] + bv;
        if (EPI == 4){
          float partner = __shfl_xor(v, 1);
          if (!(l31 & 1)){
            float rr = v / (1.f + __expf(-v)) * partner;   // silu(gate)*up
            ((unsigned short*)Cv)[(size_t)row * ldc + (gn >> 1)] = f2b(rr);
          }
        } else {
          size_t offc = (size_t)row * ldc + gn;
          if (EPI == 0)      ((float*)Cv)[offc] = v;
          else if (EPI == 1) ((unsigned short*)Cv)[offc] =
                                f2b(v + b2f(((const unsigned short*)res)[offc]));
          else if (EPI == 2) ((unsigned short*)Cv)[offc] = f2b(0.5f * v * (1.0f + erff(v * 0.70710678118f)));
          else               ((unsigned short*)Cv)[offc] = f2b(v);
        }
      }
    }
  }
}

// ---------------- RoPE + QKV split to global (full-attn layers only) ------
__global__ __launch_bounds__(256) void rope_split_kernel(
    const unsigned short* __restrict__ qkv, const float* __restrict__ cosT,
    const float* __restrict__ sinT,
    unsigned short* __restrict__ qo, unsigned short* __restrict__ ko,
    unsigned short* __restrict__ vt)
{
  __shared__ unsigned short vtile[80][128];
  int id = blockIdx.y * 16 + blockIdx.x;
  int logical = ((id & 7) << 5) + (id >> 3);
  const int h = logical & 15;
  const int s0 = (logical >> 4) * 128;
  const int t = threadIdx.x;
  const int sr = t >> 1, half = t & 1;
  const int s = s0 + sr;
  const unsigned short* row = qkv + (size_t)s * 3840 + h * 80;
  const float* crow = cosT + (size_t)s * 80;
  const float* srow = sinT + (size_t)s * 80;
  const float sgn = half ? 1.f : -1.f;
  #pragma unroll
  for (int g = 0; g < 5; ++g){
    int d  = half * 40 + g * 8;
    int dp = 40 - half * 40 + g * 8;
    short8 q8  = *(const short8*)(row + d);
    short8 k8  = *(const short8*)(row + 1280 + d);
    short8 qp8 = *(const short8*)(row + dp);
    short8 kp8 = *(const short8*)(row + 1280 + dp);
    short8 v8  = *(const short8*)(row + 2560 + d);
    f32x4 c0  = *(const f32x4*)(crow + d);
    f32x4 c1  = *(const f32x4*)(crow + d + 4);
    f32x4 sn0 = *(const f32x4*)(srow + d);
    f32x4 sn1 = *(const f32x4*)(srow + d + 4);
    float cc[8] = {c0[0], c0[1], c0[2], c0[3], c1[0], c1[1], c1[2], c1[3]};
    float ss[8] = {sn0[0], sn0[1], sn0[2], sn0[3], sn1[0], sn1[1], sn1[2], sn1[3]};
    short8 qo8, ko8;
    #pragma unroll
    for (int j = 0; j < 8; ++j){
      float qv = b2f((unsigned short)q8[j]);
      float kv = b2f((unsigned short)k8[j]);
      float qr = sgn * b2f((unsigned short)qp8[j]);
      float kr = sgn * b2f((unsigned short)kp8[j]);
      qo8[j] = (short)f2b(qv * cc[j] + qr * ss[j]);
      ko8[j] = (short)f2b(kv * cc[j] + kr * ss[j]);
      vtile[d + j][sr] = (unsigned short)v8[j];
    }
    size_t qkoff = ((size_t)h * S_LEN + s) * HDIM + d;
    *(short8*)(qo + qkoff) = qo8;
    *(short8*)(ko + qkoff) = ko8;
  }
  __syncthreads();
  #pragma unroll
  for (int it = 0; it < 5; ++it){
    int j = t + it * 256;
    int d = j >> 4, ch = j & 15;
    u32x4 v = *(const u32x4*)&vtile[d][ch * 8];
    *(u32x4*)(vt + ((size_t)h * VROWS + d) * S_LEN + s0 + ch * 8) = v;
  }
}

// ---------------- FUSED RoPE + windowed flash (6 of 8 layers) --------------
#define QKPAD 104
#define VPAD  136
__global__ __launch_bounds__(256) void rope_window_kernel(
    const unsigned short* __restrict__ qkv, const float* __restrict__ cosT,
    const float* __restrict__ sinT, unsigned short* __restrict__ out)
{
  __shared__ __align__(16) unsigned short qs[128][QKPAD];   // reused as ot
  __shared__ __align__(16) unsigned short ks[128][QKPAD];
  __shared__ __align__(16) unsigned short vtile[96][VPAD];
  unsigned short (*ot)[32][88] = (unsigned short(*)[32][88])&qs[0][0];
  int id = blockIdx.y * 16 + blockIdx.x;
  int logical = ((id & 7) << 5) + (id >> 3);
  const int h = logical & 15;
  const int s0 = (logical >> 4) * 128;
  const int t = threadIdx.x;
  {
    const int sr = t >> 1, half = t & 1;
    const int s = s0 + sr;
    const unsigned short* row = qkv + (size_t)s * 3840 + h * 80;
    const float* crow = cosT + (size_t)s * 80;
    const float* srow = sinT + (size_t)s * 80;
    const float sgn = half ? 1.f : -1.f;
    #pragma unroll
    for (int g = 0; g < 5; ++g){
      int d  = half * 40 + g * 8;
      int dp = 40 - half * 40 + g * 8;
      short8 q8  = *(const short8*)(row + d);
      short8 k8  = *(const short8*)(row + 1280 + d);
      short8 qp8 = *(const short8*)(row + dp);
      short8 kp8 = *(const short8*)(row + 1280 + dp);
      short8 v8  = *(const short8*)(row + 2560 + d);
      f32x4 c0  = *(const f32x4*)(crow + d);
      f32x4 c1  = *(const f32x4*)(crow + d + 4);
      f32x4 sn0 = *(const f32x4*)(srow + d);
      f32x4 sn1 = *(const f32x4*)(srow + d + 4);
      float cc[8] = {c0[0], c0[1], c0[2], c0[3], c1[0], c1[1], c1[2], c1[3]};
      float ss[8] = {sn0[0], sn0[1], sn0[2], sn0[3], sn1[0], sn1[1], sn1[2], sn1[3]};
      short8 qo8, ko8;
      #pragma unroll
      for (int j = 0; j < 8; ++j){
        float qv = b2f((unsigned short)q8[j]);
        float kv = b2f((unsigned short)k8[j]);
        float qr = sgn * b2f((unsigned short)qp8[j]);
        float kr = sgn * b2f((unsigned short)kp8[j]);
        qo8[j] = (short)f2b(qv * cc[j] + qr * ss[j]);
        ko8[j] = (short)f2b(kv * cc[j] + kr * ss[j]);
        vtile[d + j][sr] = (unsigned short)v8[j];
      }
      *(short8*)&qs[sr][d] = qo8;
      *(short8*)&ks[sr][d] = ko8;
    }
  }
  __syncthreads();

  const int lane = t & 63;
  const int w = t >> 6;
  const int l31 = lane & 31, lh1 = lane >> 5;
  const int qrl = w * 32;
  const int kv0 = (w >> 1) * 64;

  short8 qa[5];
  #pragma unroll
  for (int kc = 0; kc < 5; ++kc)
    qa[kc] = *(const short8*)&qs[qrl + l31][kc * 16 + lh1 * 8];
  __syncthreads();

  float m_ = -1e30f, l_ = 0.f;
  f32x16 o0 = {}, o1 = {}, o2 = {};
  const float scale = 0.11180339887498949f;

  #pragma unroll
  for (int step = 0; step < 2; ++step){
    int kvl = kv0 + step * 32;
    f32x16 sc = {};
    __builtin_amdgcn_s_setprio(1);
    #pragma unroll
    for (int kc = 0; kc < 5; ++kc){
      short8 kf = *(const short8*)&ks[kvl + l31][kc * 16 + lh1 * 8];
      sc = __builtin_amdgcn_mfma_f32_32x32x16_bf16(kf, qa[kc], sc, 0, 0, 0);
    }
    __builtin_amdgcn_s_setprio(0);
    float tmax = sc[0];
    #pragma unroll
    for (int i = 1; i < 16; ++i) tmax = fmaxf(tmax, sc[i]);
    tmax = fmaxf(tmax, __shfl_xor(tmax, 32)) * scale;
    if (!__all(tmax <= m_ + 8.f)){
      float mnew = fmaxf(m_, tmax);
      float corr = __expf(m_ - mnew);
      l_ *= corr;
      #pragma unroll
      for (int i = 0; i < 16; ++i){ o0[i] *= corr; o1[i] *= corr; o2[i] *= corr; }
      m_ = mnew;
    }
    float p[16];
    float rs = 0.f;
    #pragma unroll
    for (int i = 0; i < 16; ++i){ p[i] = __expf(sc[i] * scale - m_); rs += p[i]; }
    rs += __shfl_xor(rs, 32);
    l_ += rs;
    unsigned wd0[4], wd1[4];
    #pragma unroll
    for (int j = 0; j < 2; ++j){
      unsigned Aj = pk2(p[2 * j],     p[2 * j + 1]);
      unsigned Bj = pk2(p[4 + 2 * j], p[4 + 2 * j + 1]);
      unsigned t0 = __shfl_xor(Aj, 32);
      unsigned t1 = __shfl_xor(Bj, 32);
      wd0[j]     = lh1 ? t1 : Aj;
      wd0[2 + j] = lh1 ? Bj : t0;
      Aj = pk2(p[8 + 2 * j],  p[8 + 2 * j + 1]);
      Bj = pk2(p[12 + 2 * j], p[12 + 2 * j + 1]);
      t0 = __shfl_xor(Aj, 32);
      t1 = __shfl_xor(Bj, 32);
      wd1[j]     = lh1 ? t1 : Aj;
      wd1[2 + j] = lh1 ? Bj : t0;
    }
    __builtin_amdgcn_s_setprio(1);
    #pragma unroll
    for (int kc2 = 0; kc2 < 2; ++kc2){
      u32x4 uw = kc2 ? u32x4{wd1[0], wd1[1], wd1[2], wd1[3]}
                     : u32x4{wd0[0], wd0[1], wd0[2], wd0[3]};
      short8 pb = __builtin_bit_cast(short8, uw);
      int sv = kvl + kc2 * 16 + lh1 * 8;
      o0 = __builtin_amdgcn_mfma_f32_32x32x16_bf16(
          *(const short8*)&vtile[l31][sv],      pb, o0, 0, 0, 0);
      o1 = __builtin_amdgcn_mfma_f32_32x32x16_bf16(
          *(const short8*)&vtile[32 + l31][sv], pb, o1, 0, 0, 0);
      o2 = __builtin_amdgcn_mfma_f32_32x32x16_bf16(
          *(const short8*)&vtile[64 + l31][sv], pb, o2, 0, 0, 0);
    }
    __builtin_amdgcn_s_setprio(0);
  }

  float inv = 1.f / l_;
  #pragma unroll
  for (int r = 0; r < 16; ++r){
    int dl = (r & 3) + 8 * (r >> 2) + 4 * lh1;
    ot[w][l31][dl]      = f2b(o0[r] * inv);
    ot[w][l31][32 + dl] = f2b(o1[r] * inv);
    if (dl < 16) ot[w][l31][64 + dl] = f2b(o2[r] * inv);
  }
  int qq = lane >> 1, half2 = lane & 1;
  #pragma unroll
  for (int j = 0; j < 20; ++j){
    unsigned v = *(const unsigned*)&ot[w][qq][half2 * 40 + j * 2];
    *(unsigned*)&out[(size_t)(s0 + qrl + qq) * HID + h * HDIM + half2 * 40 + j * 2] = v;
  }
}

// ---------------- Flash attention for FULL layers (split-kv in-block) ------
__global__ __launch_bounds__(256) void flash_full_kernel(
    const unsigned short* __restrict__ q, const unsigned short* __restrict__ k,
    const unsigned short* __restrict__ vt, unsigned short* __restrict__ out)
{
  const int lane = threadIdx.x & 63;
  const int w = threadIdx.x >> 6;
  const int l31 = lane & 31, lh1 = lane >> 5;
  int id = blockIdx.y * gridDim.x + blockIdx.x;
  int logical = ((id & 7) << 7) + (id >> 3);
  const int h = logical >> 6;
  const int qr = (logical & 63) * 32;
  const unsigned short* qh = q + (size_t)h * S_LEN * HDIM;
  const unsigned short* kh = k + (size_t)h * S_LEN * HDIM;
  const unsigned short* vh = vt + (size_t)h * VROWS * S_LEN;

  short8 qa[5];
  #pragma unroll
  for (int kc = 0; kc < 5; ++kc)
    qa[kc] = *(const short8*)(qh + (size_t)(qr + l31) * HDIM + kc * 16 + lh1 * 8);

  float m_ = -1e30f, l_ = 0.f;
  f32x16 o0 = {}, o1 = {}, o2 = {};
  const float scale = 0.11180339887498949f;

  for (int kvt = w * 512; kvt < w * 512 + 512; kvt += 32){
    f32x16 sc = {};
    __builtin_amdgcn_s_setprio(1);
    #pragma unroll
    for (int kc = 0; kc < 5; ++kc){
      short8 kf = *(const short8*)(kh + (size_t)(kvt + l31) * HDIM + kc * 16 + lh1 * 8);
      sc = __builtin_amdgcn_mfma_f32_32x32x16_bf16(kf, qa[kc], sc, 0, 0, 0);
    }
    __builtin_amdgcn_s_setprio(0);
    float t = sc[0];
    #pragma unroll
    for (int i = 1; i < 16; ++i) t = fmaxf(t, sc[i]);
    t = fmaxf(t, __shfl_xor(t, 32)) * scale;
    if (!__all(t <= m_ + 8.f)){
      float mnew = fmaxf(m_, t);
      float corr = __expf(m_ - mnew);
      l_ *= corr;
      #pragma unroll
      for (int i = 0; i < 16; ++i){ o0[i] *= corr; o1[i] *= corr; o2[i] *= corr; }
      m_ = mnew;
    }
    float p[16];
    float rs = 0.f;
    #pragma unroll
    for (int i = 0; i < 16; ++i){ p[i] = __expf(sc[i] * scale - m_); rs += p[i]; }
    rs += __shfl_xor(rs, 32);
    l_ += rs;
    unsigned wd0[4], wd1[4];
    #pragma unroll
    for (int j = 0; j < 2; ++j){
      unsigned Aj = pk2(p[2 * j],     p[2 * j + 1]);
      unsigned Bj = pk2(p[4 + 2 * j], p[4 + 2 * j + 1]);
      unsigned t0 = __shfl_xor(Aj, 32);
      unsigned t1 = __shfl_xor(Bj, 32);
      wd0[j]     = lh1 ? t1 : Aj;
      wd0[2 + j] = lh1 ? Bj : t0;
      Aj = pk2(p[8 + 2 * j],  p[8 + 2 * j + 1]);
      Bj = pk2(p[12 + 2 * j], p[12 + 2 * j + 1]);
      t0 = __shfl_xor(Aj, 32);
      t1 = __shfl_xor(Bj, 32);
      wd1[j]     = lh1 ? t1 : Aj;
      wd1[2 + j] = lh1 ? Bj : t0;
    }
    __builtin_amdgcn_s_setprio(1);
    #pragma unroll
    for (int kc2 = 0; kc2 < 2; ++kc2){
      u32x4 uw = kc2 ? u32x4{wd1[0], wd1[1], wd1[2], wd1[3]}
                     : u32x4{wd0[0], wd0[1], wd0[2], wd0[3]};
      short8 pb = __builtin_bit_cast(short8, uw);
      const unsigned short* vb = vh + kvt + kc2 * 16 + lh1 * 8;
      o0 = __builtin_amdgcn_mfma_f32_32x32x16_bf16(
          *(const short8*)(vb + (size_t)(l31)      * S_LEN), pb, o0, 0, 0, 0);
      o1 = __builtin_amdgcn_mfma_f32_32x32x16_bf16(
          *(const short8*)(vb + (size_t)(32 + l31) * S_LEN), pb, o1, 0, 0, 0);
      o2 = __builtin_amdgcn_mfma_f32_32x32x16_bf16(
          *(const short8*)(vb + (size_t)(64 + l31) * S_LEN), pb, o2, 0, 0, 0);
    }
    __builtin_amdgcn_s_setprio(0);
  }

  __shared__ float of[80][33];
  __shared__ float mlsh[4][32][2];
  __shared__ float Lsh[32];
  __shared__ unsigned short ot2[32][88];
  if (lane < 32){ mlsh[w][l31][0] = m_; mlsh[w][l31][1] = l_; }
  __syncthreads();
  float M = fmaxf(fmaxf(mlsh[0][l31][0], mlsh[1][l31][0]),
                  fmaxf(mlsh[2][l31][0], mlsh[3][l31][0]));
  float L = 0.f;
  #pragma unroll
  for (int c = 0; c < 4; ++c) L += __expf(mlsh[c][l31][0] - M) * mlsh[c][l31][1];
  float wgt = __expf(m_ - M);
  if (w == 0 && lane < 32) Lsh[l31] = L;
  #pragma unroll
  for (int rnd = 0; rnd < 4; ++rnd){
    if (w == rnd){
      #pragma unroll
      for (int i = 0; i < 16; ++i){
        int dl = (i & 3) + 8 * (i >> 2) + 4 * lh1;
        if (rnd == 0){
          of[dl][l31]      = wgt * o0[i];
          of[32 + dl][l31] = wgt * o1[i];
          if (dl < 16) of[64 + dl][l31] = wgt * o2[i];
        } else {
          of[dl][l31]      += wgt * o0[i];
          of[32 + dl][l31] += wgt * o1[i];
          if (dl < 16) of[64 + dl][l31] += wgt * o2[i];
        }
      }
    }
    __syncthreads();
  }
  const int tq = threadIdx.x & 31, ds0 = (threadIdx.x >> 5) * 10;
  float Lq = Lsh[tq];
  #pragma unroll
  for (int j = 0; j < 10; ++j)
    ot2[tq][ds0 + j] = f2b(of[ds0 + j][tq] / Lq);
  __syncthreads();
  if (threadIdx.x < 64){
    int qq = threadIdx.x >> 1, half = threadIdx.x & 1;
    #pragma unroll
    for (int j2 = 0; j2 < 20; ++j2){
      unsigned v = *(const unsigned*)&ot2[qq][half * 40 + j2 * 2];
      *(unsigned*)&out[(size_t)(qr + qq) * HID + h * HDIM + half * 40 + j2 * 2] = v;
    }
  }
}

// ---------------- host ----------------------------------------------------
extern "C" void kernel_launch(void* const* d_in, const int* in_sizes, int n_in,
                              void* d_out, int out_size, void* d_ws, size_t ws_size,
                              hipStream_t stream)
{
  const float* hidden = (const float*)d_in[0];
  const float* cosT   = (const float*)d_in[3];
  const float* sinT   = (const float*)d_in[4];
  const float* qkv_w  = (const float*)d_in[5];
  const float* qkv_b  = (const float*)d_in[6];
  const float* proj_w = (const float*)d_in[7];
  const float* proj_b = (const float*)d_in[8];
  const float* norm1_w= (const float*)d_in[9];
  const float* norm2_w= (const float*)d_in[10];
  const float* gate_w = (const float*)d_in[11];
  const float* gate_b = (const float*)d_in[12];
  const float* up_w   = (const float*)d_in[13];
  const float* up_b   = (const float*)d_in[14];
  const float* down_w = (const float*)d_in[15];
  const float* down_b = (const float*)d_in[16];
  const float* ln_q_w = (const float*)d_in[17];
  const float* m0_w   = (const float*)d_in[18];
  const float* m0_b   = (const float*)d_in[19];
  const float* m2_w   = (const float*)d_in[20];
  const float* m2_b   = (const float*)d_in[21];

  char* ws = (char*)d_ws;
  size_t off = 0;
  auto carve = [&](size_t bytes)->char*{
    char* p = ws + off; off += (bytes + 255) & ~(size_t)255; return p;
  };
  unsigned short* x    = (unsigned short*)carve((size_t)S_LEN * HID * 2);
  unsigned short* hbuf = (unsigned short*)carve((size_t)S_LEN * HID * 2);
  unsigned short* qkvb = (unsigned short*)carve((size_t)S_LEN * 3840 * 2);
  unsigned short* qp   = (unsigned short*)carve((size_t)NHEADS * S_LEN * HDIM * 2);
  unsigned short* kp   = (unsigned short*)carve((size_t)NHEADS * S_LEN * HDIM * 2);
  unsigned short* vtb  = (unsigned short*)carve((size_t)NHEADS * VROWS * S_LEN * 2);
  unsigned short* ao   = (unsigned short*)carve((size_t)S_LEN * HID * 2);
  unsigned short* mlp  = (unsigned short*)carve((size_t)S_LEN * IDIMP * 2);
  unsigned short* mg   = (unsigned short*)carve((size_t)512 * MERGED * 2);
  unsigned short* wbf  = (unsigned short*)carve((size_t)203161600 * 2);
  (void)ws_size; (void)in_sizes; (void)n_in; (void)out_size;

  ConvSegs cs;
  int totalblocks = 0;
  {
    int si = 0;
    auto add = [&](int base, long long soff, long long doff, int N, int K,
                   int Np, int Kp, int rstride, int roffs){
      cs.bpre[si] = totalblocks;
      cs.srcbase[si] = base; cs.srcoff[si] = soff; cs.dstoff[si] = doff;
      cs.N[si] = N; cs.K[si] = K; cs.Kp[si] = Kp;
      cs.rstride[si] = rstride; cs.roffs[si] = roffs;
      long long groups = (long long)Np * (Kp >> 3);
      totalblocks += (int)((groups + 255) / 256);
      ++si;
    };
    for (long long i = 0; i < LAYERS; ++i){
      add(0, i * 3840LL * HID,        i * LWE + 0,        3840, HID, 3840, HID, 1, 0);
      add(1, i * (long long)HID * HID, i * LWE + 4915200,  HID, HID, HID, HID, 1, 0);
      add(2, i * (long long)IDIM * HID, i * LWE + 6553600,  IDIM, HID, IDIMP, HID, 2, 0);
      add(3, i * (long long)IDIM * HID, i * LWE + 6553600,  IDIM, HID, IDIMP, HID, 2, 1);
      add(4, i * (long long)HID * IDIM, i * LWE + 15400960, HID, IDIM, HID, IDIMP, 1, 0);
    }
    add(5, 0, 8 * LWE,            MERGED, MERGED, MERGED, MERGED, 1, 0);
    add(6, 0, 8 * LWE + 26214400, OUTD,   MERGED, OUTD,   MERGED, 1, 0);
    cs.bpre[NSEG] = totalblocks;
  }

  {
    int chunk = (totalblocks + 1) / 2;
    for (int c = 0; c < 2; ++c){
      int bs = c * chunk;
      int nb = (bs + chunk <= totalblocks) ? chunk : (totalblocks - bs);
      if (nb > 0)
        convert_all_kernel<<<nb, 256, 0, stream>>>(
            cs, bs, qkv_w, proj_w, gate_w, up_w, down_w, m0_w, m2_w, wbf);
    }
  }
  h2b_kernel<<<(int)((size_t)S_LEN * HID / 8 / 256), 256, 0, stream>>>(hidden, x);

  for (int i = 0; i < LAYERS; ++i){
    unsigned short* wl = wbf + (size_t)i * LWE;
    unsigned short* wqkv = wl;
    unsigned short* wproj= wl + 4915200;
    unsigned short* wgu  = wl + 6553600;
    unsigned short* wdown= wl + 15400960;

    rmsnorm_kernel<<<S_LEN, 256, 0, stream>>>(x, norm1_w + (size_t)i * HID, hbuf, HID);
    gemm_kernel<3,128,128,32><<<dim3(30, 16), 256, 0, stream>>>(
        hbuf, HID, wqkv, HID, qkv_b + (size_t)i * 3840, 3840,
        qkvb, 3840, nullptr, HID);
    if (i == 3 || i == 7){
      rope_split_kernel<<<dim3(NHEADS, 16), 256, 0, stream>>>(qkvb, cosT, sinT, qp, kp, vtb);
      flash_full_kernel<<<dim3(64, 16), 256, 0, stream>>>(qp, kp, vtb, ao);
    } else {
      rope_window_kernel<<<dim3(16, 16), 256, 0, stream>>>(qkvb, cosT, sinT, ao);
    }
    gemm_kernel<1,64,64,64><<<dim3(20, 32), 256, 0, stream>>>(
        ao, HID, wproj, HID, proj_b + (size_t)i * HID, HID,
        x, HID, x, HID);
    rmsnorm_kernel<<<S_LEN, 256, 0, stream>>>(x, norm2_w + (size_t)i * HID, hbuf, HID);
    gemm_kernel<4,128,128,32><<<dim3(54, 16), 256, 0, stream>>>(
        hbuf, HID, wgu, HID, gate_b + (size_t)i * IDIM, 2 * IDIM,
        mlp, IDIMP, up_b + (size_t)i * IDIM, HID);
    gemm_kernel<1,64,64,64><<<dim3(20, 32), 256, 0, stream>>>(
        mlp, IDIMP, wdown, IDIMP, down_b + (size_t)i * HID, HID,
        x, HID, x, IDIMP);
  }
  // patch merger
  unsigned short* wm0 = wbf + 8 * LWE;
  unsigned short* wm2 = wm0 + (size_t)MERGED * MERGED;
  rmsnorm_kernel<<<S_LEN, 256, 0, stream>>>(x, ln_q_w, hbuf, HID);
  gemm_kernel<2,64,64,64><<<dim3(80, 8), 256, 0, stream>>>(
      hbuf, MERGED, wm0, MERGED, m0_b, MERGED, mg, MERGED, nullptr, MERGED);
  gemm_kernel<0,64,64,64><<<dim3(56, 8), 256, 0, stream>>>(
      mg, MERGED, wm2, MERGED, m2_b, OUTD, d_out, OUTD, nullptr, MERGED);
}